// Round 4
// baseline (270.926 us; speedup 1.0000x reference)
//
#include <hip/hip_runtime.h>
#include <stdint.h>

#define DEVFN __device__ __forceinline__

typedef unsigned short u16;
typedef __bf16 bf16_t;
typedef bf16_t bf16x8 __attribute__((ext_vector_type(8)));
typedef float  f32x4  __attribute__((ext_vector_type(4)));

static constexpr int Bb = 8, Nn = 3072, Cc = 768;
static constexpr int Mr = Bb * Nn;      // 24576 rows
static constexpr int C3 = 3 * Cc;       // 2304
static constexpr int NB = 1024;         // dilation stride

DEVFN u16 f2bf_rne(float f) {
  uint32_t u = __builtin_bit_cast(uint32_t, f);
  u += 0x7FFFu + ((u >> 16) & 1u);
  return (u16)(u >> 16);
}
DEVFN float bf2f(u16 v) {
  uint32_t u = ((uint32_t)v) << 16;
  return __builtin_bit_cast(float, u);
}

// ---------------- f32 -> bf16 convert ----------------
__global__ void cvt_f32_bf16(const float4* __restrict__ in, ushort4* __restrict__ out, int n4) {
  int i = blockIdx.x * blockDim.x + threadIdx.x;
  int stride = gridDim.x * blockDim.x;
  for (; i < n4; i += stride) {
    float4 v = in[i];
    ushort4 o;
    o.x = f2bf_rne(v.x); o.y = f2bf_rne(v.y);
    o.z = f2bf_rne(v.z); o.w = f2bf_rne(v.w);
    out[i] = o;
  }
}

// ---------------- async global->LDS, 16B per lane ----------------
DEVFN void gload_lds16(const void* g, void* l) {
  __builtin_amdgcn_global_load_lds(
      (const __attribute__((address_space(1))) uint32_t*)g,
      (__attribute__((address_space(3))) uint32_t*)l,
      16, 0, 0);
}

// =====================================================================
// 256x256 bf16 NT GEMM, 8 waves, 4-slot K-slice ring, m201-style
// sub-phase schedule: per K=32 slice, TWO sub-phases of 16 MFMA each:
//   { ds_read subtile ; 2x gload_lds(slice p+3) ; [vmcnt(N) in subB] ;
//     s_barrier ; lgkmcnt(0) ; setprio(1) ; 16 MFMA ; setprio(0) ; s_barrier }
// Counted vmcnt: 12 gloads in flight steady-state, wait to 8 once per
// slice (never 0 in main loop). Trailing barrier = WAR guard on ring slot.
// Swizzle (verified conflict-free r3): LDS(r,c)=global(r, c^(((r>>1)&3)<<4)).
// Operand-swapped MFMA: lane's 4 acc regs = 4 consecutive out cols.
// =====================================================================
template <bool OUT_F32>
__global__ __launch_bounds__(512, 2)
void gemm256(const u16* __restrict__ A, const u16* __restrict__ Bw,
             void* __restrict__ Cout, const float* __restrict__ bias,
             int Ndim, int K) {
  constexpr int SLOT = 32768;
  __shared__ char lds[4 * SLOT];   // 128 KiB

  const int nTn = Ndim >> 8;
  const int nwg = gridDim.x;
  const int bid = blockIdx.x;
  const int wgid = (bid & 7) * (nwg >> 3) + (bid >> 3);   // XCD swizzle (nwg%8==0)
  const int tm = wgid / nTn, tn = wgid % nTn;

  const int t = threadIdx.x;
  const int l = t & 63;
  const int w = t >> 6;          // wave 0..7
  const int wr = w >> 2;         // M half of tile
  const int wcq = w & 3;         // N quarter of tile
  const int lr = l & 15;

  const int NPH = K >> 5;        // K=32 slices (24 here)

  // staging source (per-lane, pre-swizzled col within the 32-slice)
  const int srow = l >> 2;
  const int scol = 8 * ((l & 3) ^ ((srow >> 1) & 3));
  const u16* pA0 = A  + (size_t)(tm * 256 +       w * 16 + srow) * K + scol;
  const u16* pA1 = A  + (size_t)(tm * 256 + 128 + w * 16 + srow) * K + scol;
  const u16* pB0 = Bw + (size_t)(tn * 256 +       w * 16 + srow) * K + scol;
  const u16* pB1 = Bw + (size_t)(tn * 256 + 128 + w * 16 + srow) * K + scol;

  // ds_read per-lane offset (swizzled)
  const int lane_off = lr * 64 + (((l >> 4) * 16) ^ (((lr >> 1) & 3) << 4));

  f32x4 acc[8][4];
  #pragma unroll
  for (int m = 0; m < 8; ++m)
    #pragma unroll
    for (int n = 0; n < 4; ++n)
      acc[m][n] = f32x4{0.f, 0.f, 0.f, 0.f};

  bf16x8 afl[4], afh[4], bfr[4];

  // prologue: stage slices 0,1,2 (12 gloads/wave in flight)
  #pragma unroll
  for (int q = 0; q < 3; ++q) {
    char* dA = &lds[q * SLOT + w * 1024];
    char* dB = &lds[q * SLOT + 16384 + w * 1024];
    const size_t ko = (size_t)q * 32;
    gload_lds16(pA0 + ko, dA);
    gload_lds16(pA1 + ko, dA + 8192);
    gload_lds16(pB0 + ko, dB);
    gload_lds16(pB1 + ko, dB + 8192);
  }
  asm volatile("s_waitcnt vmcnt(8)" ::: "memory");   // slice 0 landed
  __builtin_amdgcn_s_barrier();

#define SUBA(PF)                                                              \
  do {                                                                        \
    const char* ab = &lds[(p & 3) * SLOT] + wr * 8192 + lane_off;             \
    const char* bb = &lds[(p & 3) * SLOT + 16384] + wcq * 4096 + lane_off;    \
    _Pragma("unroll")                                                         \
    for (int m = 0; m < 4; ++m)                                               \
      afl[m] = *reinterpret_cast<const bf16x8*>(ab + m * 1024);               \
    _Pragma("unroll")                                                         \
    for (int n = 0; n < 4; ++n)                                               \
      bfr[n] = *reinterpret_cast<const bf16x8*>(bb + n * 1024);               \
    if (PF) {                                                                 \
      char* dA = &lds[((p + 3) & 3) * SLOT + w * 1024];                       \
      gload_lds16(pA0 + (size_t)(p + 3) * 32, dA);                            \
      gload_lds16(pA1 + (size_t)(p + 3) * 32, dA + 8192);                     \
    }                                                                         \
    __builtin_amdgcn_sched_barrier(0);                                        \
    __builtin_amdgcn_s_barrier();                                             \
    asm volatile("s_waitcnt lgkmcnt(0)" ::: "memory");                        \
    __builtin_amdgcn_sched_barrier(0);                                        \
    __builtin_amdgcn_s_setprio(1);                                            \
    _Pragma("unroll")                                                         \
    for (int m = 0; m < 4; ++m)                                               \
      _Pragma("unroll")                                                       \
      for (int n = 0; n < 4; ++n)                                             \
        acc[m][n] = __builtin_amdgcn_mfma_f32_16x16x32_bf16(bfr[n], afl[m],   \
                                                            acc[m][n], 0,0,0);\
    __builtin_amdgcn_s_setprio(0);                                            \
    __builtin_amdgcn_s_barrier();                                             \
  } while (0)

#define SUBB(PF, VMSTR)                                                       \
  do {                                                                        \
    const char* ab = &lds[(p & 3) * SLOT] + wr * 8192 + lane_off;             \
    _Pragma("unroll")                                                         \
    for (int m = 0; m < 4; ++m)                                               \
      afh[m] = *reinterpret_cast<const bf16x8*>(ab + (m + 4) * 1024);         \
    if (PF) {                                                                 \
      char* dB = &lds[((p + 3) & 3) * SLOT + 16384 + w * 1024];               \
      gload_lds16(pB0 + (size_t)(p + 3) * 32, dB);                            \
      gload_lds16(pB1 + (size_t)(p + 3) * 32, dB + 8192);                     \
    }                                                                         \
    asm volatile(VMSTR ::: "memory");                                         \
    __builtin_amdgcn_sched_barrier(0);                                        \
    __builtin_amdgcn_s_barrier();                                             \
    asm volatile("s_waitcnt lgkmcnt(0)" ::: "memory");                        \
    __builtin_amdgcn_sched_barrier(0);                                        \
    __builtin_amdgcn_s_setprio(1);                                            \
    _Pragma("unroll")                                                         \
    for (int m = 0; m < 4; ++m)                                               \
      _Pragma("unroll")                                                       \
      for (int n = 0; n < 4; ++n)                                             \
        acc[m + 4][n] = __builtin_amdgcn_mfma_f32_16x16x32_bf16(bfr[n], afh[m],\
                                                            acc[m + 4][n], 0,0,0);\
    __builtin_amdgcn_s_setprio(0);                                            \
    __builtin_amdgcn_s_barrier();                                             \
  } while (0)

  int p = 0;
  for (; p < NPH - 3; ++p) {               // steady state: 12 gloads in flight
    SUBA(true);
    SUBB(true, "s_waitcnt vmcnt(8)");      // slice p+1 landed; 8 stay in flight
  }
  SUBA(false); SUBB(false, "s_waitcnt vmcnt(4)"); ++p;   // p = NPH-3
  SUBA(false); SUBB(false, "s_waitcnt vmcnt(0)"); ++p;   // p = NPH-2
  SUBA(false); SUBB(false, "");                          // p = NPH-1
#undef SUBA
#undef SUBB

  // epilogue (operand-swapped layout): lane l, frag (m,n), reg j holds
  //   C[row = m*16 + (l&15)][col = n*16 + (l>>4)*4 + j]
  const int grow0 = tm * 256 + wr * 128 + lr;
  const int gcol0 = tn * 256 + wcq * 64 + (l >> 4) * 4;
  #pragma unroll
  for (int m = 0; m < 8; ++m) {
    const int row = grow0 + m * 16;
    #pragma unroll
    for (int n = 0; n < 4; ++n) {
      const int col = gcol0 + n * 16;
      if constexpr (OUT_F32) {
        float* O = (float*)Cout;
        const float4 bv = *reinterpret_cast<const float4*>(&bias[col]);
        float4 o;
        o.x = acc[m][n][0] + bv.x;
        o.y = acc[m][n][1] + bv.y;
        o.z = acc[m][n][2] + bv.z;
        o.w = acc[m][n][3] + bv.w;
        *reinterpret_cast<float4*>(&O[(size_t)row * Ndim + col]) = o;
      } else {
        u16* O = (u16*)Cout;
        ushort4 o;
        o.x = f2bf_rne(acc[m][n][0]);
        o.y = f2bf_rne(acc[m][n][1]);
        o.z = f2bf_rne(acc[m][n][2]);
        o.w = f2bf_rne(acc[m][n][3]);
        *reinterpret_cast<ushort4*>(&O[(size_t)row * Ndim + col]) = o;
      }
    }
  }
}

// ---------------- local 3x3 dilated attention, one wave per window ----------------
__global__ __launch_bounds__(256)
void attn_local(const u16* __restrict__ qkv, u16* __restrict__ y) {
  const int t = threadIdx.x;
  const int wv = t >> 6, lane = t & 63;
  int wid = blockIdx.x * 4 + wv;
  const int w = wid & (NB - 1); wid >>= 10;
  const int head = wid & 3; wid >>= 2;
  const int b = wid & 7; wid >>= 3;
  const int dil = wid;

  const int colq = dil * 256 + head * 64 + lane;
  float q[3], k[3], v[3];
  #pragma unroll
  for (int i = 0; i < 3; ++i) {
    const size_t row = (size_t)(b * Nn + i * NB + w) * C3;
    q[i] = bf2f(qkv[row + colq]);
    k[i] = bf2f(qkv[row + 768 + colq]);
    v[i] = bf2f(qkv[row + 1536 + colq]);
  }

  float s[3][3];
  #pragma unroll
  for (int i = 0; i < 3; ++i)
    #pragma unroll
    for (int j = 0; j < 3; ++j) {
      float p = q[i] * k[j];
      #pragma unroll
      for (int off = 32; off > 0; off >>= 1)
        p += __shfl_xor(p, off, 64);
      s[i][j] = p * 0.125f;
    }

  #pragma unroll
  for (int i = 0; i < 3; ++i) {
    const float mx = fmaxf(fmaxf(s[i][0], s[i][1]), s[i][2]);
    const float e0 = __expf(s[i][0] - mx);
    const float e1 = __expf(s[i][1] - mx);
    const float e2 = __expf(s[i][2] - mx);
    const float inv = 1.0f / (e0 + e1 + e2);
    const float o = (e0 * v[0] + e1 * v[1] + e2 * v[2]) * inv;
    const int linear = head * 192 + i * 64 + lane;
    const int nout = w * 3 + (linear >> 8);
    const int dd = linear & 255;
    y[(size_t)(b * Nn + nout) * Cc + dil * 256 + dd] = f2bf_rne(o);
  }
}

extern "C" void kernel_launch(void* const* d_in, const int* in_sizes, int n_in,
                              void* d_out, int out_size, void* d_ws, size_t ws_size,
                              hipStream_t stream) {
  const float* x      = (const float*)d_in[0];
  const float* qkv_w  = (const float*)d_in[1];
  const float* proj_w = (const float*)d_in[2];
  const float* proj_b = (const float*)d_in[3];

  char* ws = (char*)d_ws;
  u16* wq_b = (u16*)(ws);                      //  2304*768 bf16
  u16* wp_b = (u16*)(ws + 3538944);            //   768*768 bf16
  u16* xb   = (u16*)(ws + 4718592);            // 24576*768 bf16 (reused as yb)
  u16* qkvb = (u16*)(ws + 42467328);           // 24576*2304 bf16
  u16* yb   = xb;

  cvt_f32_bf16<<<2048, 256, 0, stream>>>((const float4*)x,      (ushort4*)xb,   Mr * Cc / 4);
  cvt_f32_bf16<<<512,  256, 0, stream>>>((const float4*)qkv_w,  (ushort4*)wq_b, C3 * Cc / 4);
  cvt_f32_bf16<<<256,  256, 0, stream>>>((const float4*)proj_w, (ushort4*)wp_b, Cc * Cc / 4);

  // GEMM1: qkvb[M,2304] = xb[M,768] @ wq_b[2304,768]^T   (864 blocks)
  gemm256<false><<<(Mr / 256) * (C3 / 256), 512, 0, stream>>>(xb, wq_b, qkvb, nullptr, C3, Cc);

  // attention: 98304 windows, 4 per block
  attn_local<<<(3 * 8 * 4 * 1024) / 4, 256, 0, stream>>>(qkvb, yb);

  // GEMM2: out[M,768] = yb[M,768] @ wp_b[768,768]^T + proj_b   (288 blocks)
  gemm256<true><<<(Mr / 256) * (Cc / 256), 512, 0, stream>>>(yb, wp_b, d_out, proj_b, Cc, Cc);
}

// Round 6
// 263.657 us; speedup vs baseline: 1.0276x; 1.0276x over previous
//
#include <hip/hip_runtime.h>
#include <stdint.h>

#define DEVFN __device__ __forceinline__

typedef unsigned short u16;
typedef __bf16 bf16_t;
typedef bf16_t bf16x8 __attribute__((ext_vector_type(8)));
typedef float  f32x4  __attribute__((ext_vector_type(4)));

static constexpr int Bb = 8, Nn = 3072, Cc = 768;
static constexpr int Mr = Bb * Nn;      // 24576 rows
static constexpr int C3 = 3 * Cc;       // 2304
static constexpr int NB = 1024;         // dilation stride

DEVFN u16 f2bf_rne(float f) {
  uint32_t u = __builtin_bit_cast(uint32_t, f);
  u += 0x7FFFu + ((u >> 16) & 1u);
  return (u16)(u >> 16);
}
DEVFN float bf2f(u16 v) {
  uint32_t u = ((uint32_t)v) << 16;
  return __builtin_bit_cast(float, u);
}

// ---------------- f32 -> bf16 convert ----------------
__global__ void cvt_f32_bf16(const float4* __restrict__ in, ushort4* __restrict__ out, int n4) {
  int i = blockIdx.x * blockDim.x + threadIdx.x;
  int stride = gridDim.x * blockDim.x;
  for (; i < n4; i += stride) {
    float4 v = in[i];
    ushort4 o;
    o.x = f2bf_rne(v.x); o.y = f2bf_rne(v.y);
    o.z = f2bf_rne(v.z); o.w = f2bf_rne(v.w);
    out[i] = o;
  }
}

// ---------------- async global->LDS, 16B per lane ----------------
DEVFN void gload_lds16(const void* g, void* l) {
  __builtin_amdgcn_global_load_lds(
      (const __attribute__((address_space(1))) uint32_t*)g,
      (__attribute__((address_space(3))) uint32_t*)l,
      16, 0, 0);
}

// =====================================================================
// 128x128 bf16 NT GEMM, 4 waves, 3-slot K-slice ring, 3 blocks/CU.
//   C[M,N] = A[M,K] * B[N,K]^T (+bias, f32 out) or bf16 out.
// Design point: co-residency (3 blocks x 4 waves = 12 waves/CU) hides
// barrier/latency stalls via cross-block overlap (m114) instead of a
// fragile intra-block phase schedule (R3/R4 regressions at 1 block/CU).
// LDS: 3 slots x (A 8K + B 8K) = 48 KB. Prefetch 2 slices ahead,
// counted vmcnt(8) steady state (never drains the ring).
// Swizzle sigma(r)=(r>>1)&3 on 64B rows: conflict-free ds_read_b128
// (verified R3: SQ_LDS_BANK_CONFLICT = 0).
// Operand-swapped MFMA: lane's 4 acc regs = 4 consecutive out cols.
// R5 bug fixed: ring-slot index (p+2)%3 was computed as slot+2=4 for
// slot=2 -> OOB LDS write into Bs[1]. Now a proper wrap.
// =====================================================================
template <bool OUT_F32>
__global__ __launch_bounds__(256, 3)
void gemm128(const u16* __restrict__ A, const u16* __restrict__ Bw,
             void* __restrict__ Cout, const float* __restrict__ bias,
             int Ndim, int K) {
  __shared__ u16 As[3][128 * 32];   // 3 x 8 KB
  __shared__ u16 Bs[3][128 * 32];   // 3 x 8 KB

  const int nTn = Ndim >> 7;
  const int nwg = gridDim.x;
  const int bid = blockIdx.x;
  const int wgid = (bid & 7) * (nwg >> 3) + (bid >> 3);   // XCD swizzle (nwg%8==0)
  const int tm = wgid / nTn, tn = wgid % nTn;

  const int t = threadIdx.x;
  const int l = t & 63;
  const int w = t >> 6;          // wave 0..3
  const int wrh = w >> 1;        // A-row half (0/1)
  const int wch = w & 1;         // B-row (out-col) half (0/1)
  const int lr = l & 15;

  const int NPH = K >> 5;        // K=32 slices (24 here)

  // staging: thread t stages chunks t and t+256; chunk c = row c>>2,
  // k-chunk c&3 (16B). Global col pre-swizzled so LDS dest stays linear.
  const int srow = t >> 2;
  const int scol = 8 * ((t & 3) ^ ((srow >> 1) & 3));
  const u16* pA0 = A  + (size_t)(tm * 128 +      srow) * K + scol;
  const u16* pA1 = A  + (size_t)(tm * 128 + 64 + srow) * K + scol;
  const u16* pB0 = Bw + (size_t)(tn * 128 +      srow) * K + scol;
  const u16* pB1 = Bw + (size_t)(tn * 128 + 64 + srow) * K + scol;

  // ds_read per-lane byte offset (swizzled); row-within-frag = lr,
  // k-part (l>>4)*16B; frag row-offsets (m*16, wrh*64) are mult-of-8 so
  // sigma depends only on lr.
  const int lane_off = lr * 64 + (((l >> 4) * 16) ^ (((lr >> 1) & 3) << 4));

  f32x4 acc[4][4];
  #pragma unroll
  for (int m = 0; m < 4; ++m)
    #pragma unroll
    for (int n = 0; n < 4; ++n)
      acc[m][n] = f32x4{0.f, 0.f, 0.f, 0.f};

  // prologue: stage slices 0,1 (8 gloads/wave in flight)
  #pragma unroll
  for (int q = 0; q < 2; ++q) {
    const size_t ko = (size_t)q * 32;
    gload_lds16(pA0 + ko, &As[q][(size_t)t * 8]);
    gload_lds16(pA1 + ko, &As[q][(size_t)(t + 256) * 8]);
    gload_lds16(pB0 + ko, &Bs[q][(size_t)t * 8]);
    gload_lds16(pB1 + ko, &Bs[q][(size_t)(t + 256) * 8]);
  }

  int slot = 0;
  for (int p = 0; p < NPH; ++p) {
    // stage slice p+2 into slot (p+2)%3 (freed by iter p-1's trailing barrier)
    if (p + 2 < NPH) {
      int ps = slot + 2; if (ps >= 3) ps -= 3;             // (p+2)%3
      const size_t ko = (size_t)(p + 2) * 32;
      gload_lds16(pA0 + ko, &As[ps][(size_t)t * 8]);
      gload_lds16(pA1 + ko, &As[ps][(size_t)(t + 256) * 8]);
      gload_lds16(pB0 + ko, &Bs[ps][(size_t)t * 8]);
      gload_lds16(pB1 + ko, &Bs[ps][(size_t)(t + 256) * 8]);
      asm volatile("s_waitcnt vmcnt(8)" ::: "memory");   // slice p landed; 8 in flight
    } else if (p + 2 == NPH) {
      asm volatile("s_waitcnt vmcnt(4)" ::: "memory");   // slice p landed
    } else {
      asm volatile("s_waitcnt vmcnt(0)" ::: "memory");   // last slice landed
    }
    __builtin_amdgcn_s_barrier();   // all waves' slice-p loads retired -> visible

    const char* ab = (const char*)As[slot] + wrh * 4096 + lane_off;
    const char* bb = (const char*)Bs[slot] + wch * 4096 + lane_off;
    bf16x8 af[4], bf[4];
    #pragma unroll
    for (int m = 0; m < 4; ++m)
      af[m] = *reinterpret_cast<const bf16x8*>(ab + m * 1024);
    #pragma unroll
    for (int n = 0; n < 4; ++n)
      bf[n] = *reinterpret_cast<const bf16x8*>(bb + n * 1024);

    __builtin_amdgcn_s_setprio(1);
    #pragma unroll
    for (int m = 0; m < 4; ++m)
      #pragma unroll
      for (int n = 0; n < 4; ++n)
        acc[m][n] = __builtin_amdgcn_mfma_f32_16x16x32_bf16(bf[n], af[m],
                                                            acc[m][n], 0, 0, 0);
    __builtin_amdgcn_s_setprio(0);
    __builtin_amdgcn_s_barrier();   // WAR guard: slot reused at iter p+1's stage

    slot = (slot == 2) ? 0 : slot + 1;
  }

  // epilogue (operand-swapped layout): lane l, frag (m,n), reg j holds
  //   C[row = m*16 + (l&15)][col = n*16 + (l>>4)*4 + j] -> vector stores
  const int grow0 = tm * 128 + wrh * 64 + lr;
  const int gcol0 = tn * 128 + wch * 64 + (l >> 4) * 4;
  #pragma unroll
  for (int m = 0; m < 4; ++m) {
    const int row = grow0 + m * 16;
    #pragma unroll
    for (int n = 0; n < 4; ++n) {
      const int col = gcol0 + n * 16;
      if constexpr (OUT_F32) {
        float* O = (float*)Cout;
        const float4 bv = *reinterpret_cast<const float4*>(&bias[col]);
        float4 o;
        o.x = acc[m][n][0] + bv.x;
        o.y = acc[m][n][1] + bv.y;
        o.z = acc[m][n][2] + bv.z;
        o.w = acc[m][n][3] + bv.w;
        *reinterpret_cast<float4*>(&O[(size_t)row * Ndim + col]) = o;
      } else {
        u16* O = (u16*)Cout;
        ushort4 o;
        o.x = f2bf_rne(acc[m][n][0]);
        o.y = f2bf_rne(acc[m][n][1]);
        o.z = f2bf_rne(acc[m][n][2]);
        o.w = f2bf_rne(acc[m][n][3]);
        *reinterpret_cast<ushort4*>(&O[(size_t)row * Ndim + col]) = o;
      }
    }
  }
}

// ---------------- local 3x3 dilated attention, one wave per window ----------------
__global__ __launch_bounds__(256)
void attn_local(const u16* __restrict__ qkv, u16* __restrict__ y) {
  const int t = threadIdx.x;
  const int wv = t >> 6, lane = t & 63;
  int wid = blockIdx.x * 4 + wv;
  const int w = wid & (NB - 1); wid >>= 10;
  const int head = wid & 3; wid >>= 2;
  const int b = wid & 7; wid >>= 3;
  const int dil = wid;

  const int colq = dil * 256 + head * 64 + lane;
  float q[3], k[3], v[3];
  #pragma unroll
  for (int i = 0; i < 3; ++i) {
    const size_t row = (size_t)(b * Nn + i * NB + w) * C3;
    q[i] = bf2f(qkv[row + colq]);
    k[i] = bf2f(qkv[row + 768 + colq]);
    v[i] = bf2f(qkv[row + 1536 + colq]);
  }

  float s[3][3];
  #pragma unroll
  for (int i = 0; i < 3; ++i)
    #pragma unroll
    for (int j = 0; j < 3; ++j) {
      float p = q[i] * k[j];
      #pragma unroll
      for (int off = 32; off > 0; off >>= 1)
        p += __shfl_xor(p, off, 64);
      s[i][j] = p * 0.125f;
    }

  #pragma unroll
  for (int i = 0; i < 3; ++i) {
    const float mx = fmaxf(fmaxf(s[i][0], s[i][1]), s[i][2]);
    const float e0 = __expf(s[i][0] - mx);
    const float e1 = __expf(s[i][1] - mx);
    const float e2 = __expf(s[i][2] - mx);
    const float inv = 1.0f / (e0 + e1 + e2);
    const float o = (e0 * v[0] + e1 * v[1] + e2 * v[2]) * inv;
    const int linear = head * 192 + i * 64 + lane;
    const int nout = w * 3 + (linear >> 8);
    const int dd = linear & 255;
    y[(size_t)(b * Nn + nout) * Cc + dil * 256 + dd] = f2bf_rne(o);
  }
}

extern "C" void kernel_launch(void* const* d_in, const int* in_sizes, int n_in,
                              void* d_out, int out_size, void* d_ws, size_t ws_size,
                              hipStream_t stream) {
  const float* x      = (const float*)d_in[0];
  const float* qkv_w  = (const float*)d_in[1];
  const float* proj_w = (const float*)d_in[2];
  const float* proj_b = (const float*)d_in[3];

  char* ws = (char*)d_ws;
  u16* wq_b = (u16*)(ws);                      //  2304*768 bf16
  u16* wp_b = (u16*)(ws + 3538944);            //   768*768 bf16
  u16* xb   = (u16*)(ws + 4718592);            // 24576*768 bf16 (reused as yb)
  u16* qkvb = (u16*)(ws + 42467328);           // 24576*2304 bf16
  u16* yb   = xb;

  cvt_f32_bf16<<<2048, 256, 0, stream>>>((const float4*)x,      (ushort4*)xb,   Mr * Cc / 4);
  cvt_f32_bf16<<<512,  256, 0, stream>>>((const float4*)qkv_w,  (ushort4*)wq_b, C3 * Cc / 4);
  cvt_f32_bf16<<<256,  256, 0, stream>>>((const float4*)proj_w, (ushort4*)wp_b, Cc * Cc / 4);

  // GEMM1: qkvb[M,2304] = xb[M,768] @ wq_b[2304,768]^T   (3456 blocks)
  gemm128<false><<<(Mr / 128) * (C3 / 128), 256, 0, stream>>>(xb, wq_b, qkvb, nullptr, C3, Cc);

  // attention: 98304 windows, 4 per block
  attn_local<<<(3 * 8 * 4 * 1024) / 4, 256, 0, stream>>>(qkvb, yb);

  // GEMM2: out[M,768] = yb[M,768] @ wp_b[768,768]^T + proj_b   (1152 blocks)
  gemm128<true><<<(Mr / 128) * (Cc / 128), 256, 0, stream>>>(yb, wp_b, d_out, proj_b, Cc, Cc);
}

// Round 7
// 255.230 us; speedup vs baseline: 1.0615x; 1.0330x over previous
//
#include <hip/hip_runtime.h>
#include <stdint.h>

#define DEVFN __device__ __forceinline__

typedef unsigned short u16;
typedef __bf16 bf16_t;
typedef bf16_t bf16x8 __attribute__((ext_vector_type(8)));
typedef float  f32x4  __attribute__((ext_vector_type(4)));

static constexpr int Bb = 8, Nn = 3072, Cc = 768;
static constexpr int Mr = Bb * Nn;      // 24576 rows
static constexpr int C3 = 3 * Cc;       // 2304
static constexpr int NB = 1024;         // dilation stride

DEVFN u16 f2bf_rne(float f) {
  uint32_t u = __builtin_bit_cast(uint32_t, f);
  u += 0x7FFFu + ((u >> 16) & 1u);
  return (u16)(u >> 16);
}
DEVFN float bf2f(u16 v) {
  uint32_t u = ((uint32_t)v) << 16;
  return __builtin_bit_cast(float, u);
}

// ---------------- fused f32 -> bf16 converts (x, qkv_w, proj_w) ----------------
__global__ void cvt_all(const float4* __restrict__ x, const float4* __restrict__ wq,
                        const float4* __restrict__ wp, ushort4* __restrict__ xb,
                        ushort4* __restrict__ wqb, ushort4* __restrict__ wpb) {
  const int NX = Mr * Cc / 4, NQ = C3 * Cc / 4, NP = Cc * Cc / 4;
  int i = blockIdx.x * blockDim.x + threadIdx.x;
  const int stride = gridDim.x * blockDim.x;
  for (; i < NX + NQ + NP; i += stride) {
    const float4* src; ushort4* dst; int j;
    if (i < NX)           { src = x;  dst = xb;  j = i; }
    else if (i < NX + NQ) { src = wq; dst = wqb; j = i - NX; }
    else                  { src = wp; dst = wpb; j = i - NX - NQ; }
    float4 v = src[j];
    ushort4 o;
    o.x = f2bf_rne(v.x); o.y = f2bf_rne(v.y);
    o.z = f2bf_rne(v.z); o.w = f2bf_rne(v.w);
    dst[j] = o;
  }
}

// ---------------- async global->LDS, 16B per lane ----------------
DEVFN void gload_lds16(const void* g, void* l) {
  __builtin_amdgcn_global_load_lds(
      (const __attribute__((address_space(1))) uint32_t*)g,
      (__attribute__((address_space(3))) uint32_t*)l,
      16, 0, 0);
}

// =====================================================================
// 256x256 bf16 NT GEMM, 1024 threads / 16 waves (4x4 wave grid, 64x64
// per wave), 4-slot K-slice ring, counted vmcnt.
// Rationale (R6 post-mortem): per-slice LDS-read serialization is the
// bottleneck; 4 waves/SIMD after each barrier gives the SIMD 4
// independent ds_read->MFMA streams to interleave (vs 2 in the 8-wave
// config), hiding slice-start LDS latency without fragile scheduling.
// Staging: 2 gload_lds per thread per slice (A 16KB + B 16KB over 1024
// threads). Ring: stage p+2, vmcnt(4) -> slice p landed, 1 barrier/slice.
// Swizzle sigma(r)=(r>>1)&3 on 64B rows (conflict-free, verified R3/R6).
// Operand-swapped MFMA -> vectorized stores (verified R3/R6).
// =====================================================================
template <bool OUT_F32>
__global__ __launch_bounds__(1024)
void gemm256w16(const u16* __restrict__ A, const u16* __restrict__ Bw,
                void* __restrict__ Cout, const float* __restrict__ bias,
                int Ndim, int K) {
  __shared__ u16 As[4][8192];   // 4 x 16 KB
  __shared__ u16 Bs[4][8192];   // 4 x 16 KB

  const int nTn = Ndim >> 8;
  const int nwg = gridDim.x;
  const int bid = blockIdx.x;
  const int wgid = (bid & 7) * (nwg >> 3) + (bid >> 3);   // XCD swizzle (nwg%8==0)
  const int tm = wgid / nTn, tn = wgid % nTn;

  const int t = threadIdx.x;
  const int l = t & 63;
  const int w = t >> 6;          // wave 0..15
  const int wrow = w >> 2;       // A-row quarter (0..3)
  const int wcol = w & 3;        // out-col quarter (0..3)
  const int lr = l & 15;

  const int NPH = K >> 5;        // K=32 slices (24)

  // staging: thread t stages one 16B chunk of A and one of B per slice.
  // chunk t = row t>>2, k-chunk t&3; global col pre-swizzled so the
  // linear gload_lds dest + swizzled ds_read form the same involution.
  const int srow = t >> 2;                            // 0..255
  const int scol = 8 * ((t & 3) ^ ((srow >> 1) & 3));
  const u16* pA = A  + (size_t)(tm * 256 + srow) * K + scol;
  const u16* pB = Bw + (size_t)(tn * 256 + srow) * K + scol;

  // swizzled ds_read per-lane byte offset (row = base + lr, base mult 16
  // -> sigma depends on lr only): 2 lanes per 16B slot -> conflict-free.
  const int lane_off = lr * 64 + (((l >> 4) * 16) ^ (((lr >> 1) & 3) << 4));

  f32x4 acc[4][4];
  #pragma unroll
  for (int m = 0; m < 4; ++m)
    #pragma unroll
    for (int n = 0; n < 4; ++n)
      acc[m][n] = f32x4{0.f, 0.f, 0.f, 0.f};

  // prologue: stage slices 0,1 (4 gloads/thread in flight)
  #pragma unroll
  for (int q = 0; q < 2; ++q) {
    const size_t ko = (size_t)q * 32;
    gload_lds16(pA + ko, &As[q][(size_t)t * 8]);
    gload_lds16(pB + ko, &Bs[q][(size_t)t * 8]);
  }

  for (int p = 0; p < NPH; ++p) {
    const int slot = p & 3;
    if (p + 2 < NPH) {
      const int ps = (p + 2) & 3;      // WAR-safe: last read at p-2, barrier at p-1
      const size_t ko = (size_t)(p + 2) * 32;
      gload_lds16(pA + ko, &As[ps][(size_t)t * 8]);
      gload_lds16(pB + ko, &Bs[ps][(size_t)t * 8]);
      asm volatile("s_waitcnt vmcnt(4)" ::: "memory");   // slice p landed
    } else if (p + 2 == NPH) {
      asm volatile("s_waitcnt vmcnt(2)" ::: "memory");
    } else {
      asm volatile("s_waitcnt vmcnt(0)" ::: "memory");
    }
    __builtin_amdgcn_s_barrier();

    const char* ab = (const char*)As[slot] + wrow * 4096 + lane_off;
    const char* bb = (const char*)Bs[slot] + wcol * 4096 + lane_off;
    bf16x8 af[4], bf[4];
    #pragma unroll
    for (int m = 0; m < 4; ++m)
      af[m] = *reinterpret_cast<const bf16x8*>(ab + m * 1024);
    #pragma unroll
    for (int n = 0; n < 4; ++n)
      bf[n] = *reinterpret_cast<const bf16x8*>(bb + n * 1024);

    __builtin_amdgcn_s_setprio(1);
    #pragma unroll
    for (int m = 0; m < 4; ++m)
      #pragma unroll
      for (int n = 0; n < 4; ++n)
        acc[m][n] = __builtin_amdgcn_mfma_f32_16x16x32_bf16(bf[n], af[m],
                                                            acc[m][n], 0, 0, 0);
    __builtin_amdgcn_s_setprio(0);
    // no trailing barrier needed: staging into slot (p+2)&3 happens after
    // the NEXT iteration's leading barrier, one full slice after its last read.
  }

  // epilogue (operand-swapped layout): lane l, frag (m,n), reg j holds
  //   C[row = m*16 + (l&15)][col = n*16 + (l>>4)*4 + j] -> vector stores
  const int grow0 = tm * 256 + wrow * 64 + lr;
  const int gcol0 = tn * 256 + wcol * 64 + (l >> 4) * 4;
  #pragma unroll
  for (int m = 0; m < 4; ++m) {
    const int row = grow0 + m * 16;
    #pragma unroll
    for (int n = 0; n < 4; ++n) {
      const int col = gcol0 + n * 16;
      if constexpr (OUT_F32) {
        float* O = (float*)Cout;
        const float4 bv = *reinterpret_cast<const float4*>(&bias[col]);
        float4 o;
        o.x = acc[m][n][0] + bv.x;
        o.y = acc[m][n][1] + bv.y;
        o.z = acc[m][n][2] + bv.z;
        o.w = acc[m][n][3] + bv.w;
        *reinterpret_cast<float4*>(&O[(size_t)row * Ndim + col]) = o;
      } else {
        u16* O = (u16*)Cout;
        ushort4 o;
        o.x = f2bf_rne(acc[m][n][0]);
        o.y = f2bf_rne(acc[m][n][1]);
        o.z = f2bf_rne(acc[m][n][2]);
        o.w = f2bf_rne(acc[m][n][3]);
        *reinterpret_cast<ushort4*>(&O[(size_t)row * Ndim + col]) = o;
      }
    }
  }
}

// =====================================================================
// 128x128 bf16 NT GEMM, 4 waves, 3-slot ring, 3 blocks/CU (R6, verified).
// Used for GEMM2 (1152 blocks -> decent tail at 768 concurrent).
// =====================================================================
template <bool OUT_F32>
__global__ __launch_bounds__(256, 3)
void gemm128(const u16* __restrict__ A, const u16* __restrict__ Bw,
             void* __restrict__ Cout, const float* __restrict__ bias,
             int Ndim, int K) {
  __shared__ u16 As[3][128 * 32];
  __shared__ u16 Bs[3][128 * 32];

  const int nTn = Ndim >> 7;
  const int nwg = gridDim.x;
  const int bid = blockIdx.x;
  const int wgid = (bid & 7) * (nwg >> 3) + (bid >> 3);
  const int tm = wgid / nTn, tn = wgid % nTn;

  const int t = threadIdx.x;
  const int l = t & 63;
  const int w = t >> 6;
  const int wrh = w >> 1;
  const int wch = w & 1;
  const int lr = l & 15;

  const int NPH = K >> 5;

  const int srow = t >> 2;
  const int scol = 8 * ((t & 3) ^ ((srow >> 1) & 3));
  const u16* pA0 = A  + (size_t)(tm * 128 +      srow) * K + scol;
  const u16* pA1 = A  + (size_t)(tm * 128 + 64 + srow) * K + scol;
  const u16* pB0 = Bw + (size_t)(tn * 128 +      srow) * K + scol;
  const u16* pB1 = Bw + (size_t)(tn * 128 + 64 + srow) * K + scol;

  const int lane_off = lr * 64 + (((l >> 4) * 16) ^ (((lr >> 1) & 3) << 4));

  f32x4 acc[4][4];
  #pragma unroll
  for (int m = 0; m < 4; ++m)
    #pragma unroll
    for (int n = 0; n < 4; ++n)
      acc[m][n] = f32x4{0.f, 0.f, 0.f, 0.f};

  #pragma unroll
  for (int q = 0; q < 2; ++q) {
    const size_t ko = (size_t)q * 32;
    gload_lds16(pA0 + ko, &As[q][(size_t)t * 8]);
    gload_lds16(pA1 + ko, &As[q][(size_t)(t + 256) * 8]);
    gload_lds16(pB0 + ko, &Bs[q][(size_t)t * 8]);
    gload_lds16(pB1 + ko, &Bs[q][(size_t)(t + 256) * 8]);
  }

  int slot = 0;
  for (int p = 0; p < NPH; ++p) {
    if (p + 2 < NPH) {
      int ps = slot + 2; if (ps >= 3) ps -= 3;
      const size_t ko = (size_t)(p + 2) * 32;
      gload_lds16(pA0 + ko, &As[ps][(size_t)t * 8]);
      gload_lds16(pA1 + ko, &As[ps][(size_t)(t + 256) * 8]);
      gload_lds16(pB0 + ko, &Bs[ps][(size_t)t * 8]);
      gload_lds16(pB1 + ko, &Bs[ps][(size_t)(t + 256) * 8]);
      asm volatile("s_waitcnt vmcnt(8)" ::: "memory");
    } else if (p + 2 == NPH) {
      asm volatile("s_waitcnt vmcnt(4)" ::: "memory");
    } else {
      asm volatile("s_waitcnt vmcnt(0)" ::: "memory");
    }
    __builtin_amdgcn_s_barrier();

    const char* ab = (const char*)As[slot] + wrh * 4096 + lane_off;
    const char* bb = (const char*)Bs[slot] + wch * 4096 + lane_off;
    bf16x8 af[4], bf[4];
    #pragma unroll
    for (int m = 0; m < 4; ++m)
      af[m] = *reinterpret_cast<const bf16x8*>(ab + m * 1024);
    #pragma unroll
    for (int n = 0; n < 4; ++n)
      bf[n] = *reinterpret_cast<const bf16x8*>(bb + n * 1024);

    __builtin_amdgcn_s_setprio(1);
    #pragma unroll
    for (int m = 0; m < 4; ++m)
      #pragma unroll
      for (int n = 0; n < 4; ++n)
        acc[m][n] = __builtin_amdgcn_mfma_f32_16x16x32_bf16(bf[n], af[m],
                                                            acc[m][n], 0, 0, 0);
    __builtin_amdgcn_s_setprio(0);
    __builtin_amdgcn_s_barrier();

    slot = (slot == 2) ? 0 : slot + 1;
  }

  const int grow0 = tm * 128 + wrh * 64 + lr;
  const int gcol0 = tn * 128 + wch * 64 + (l >> 4) * 4;
  #pragma unroll
  for (int m = 0; m < 4; ++m) {
    const int row = grow0 + m * 16;
    #pragma unroll
    for (int n = 0; n < 4; ++n) {
      const int col = gcol0 + n * 16;
      if constexpr (OUT_F32) {
        float* O = (float*)Cout;
        const float4 bv = *reinterpret_cast<const float4*>(&bias[col]);
        float4 o;
        o.x = acc[m][n][0] + bv.x;
        o.y = acc[m][n][1] + bv.y;
        o.z = acc[m][n][2] + bv.z;
        o.w = acc[m][n][3] + bv.w;
        *reinterpret_cast<float4*>(&O[(size_t)row * Ndim + col]) = o;
      } else {
        u16* O = (u16*)Cout;
        ushort4 o;
        o.x = f2bf_rne(acc[m][n][0]);
        o.y = f2bf_rne(acc[m][n][1]);
        o.z = f2bf_rne(acc[m][n][2]);
        o.w = f2bf_rne(acc[m][n][3]);
        *reinterpret_cast<ushort4*>(&O[(size_t)row * Ndim + col]) = o;
      }
    }
  }
}

// ---------------- local 3x3 dilated attention, one wave per window ----------------
__global__ __launch_bounds__(256)
void attn_local(const u16* __restrict__ qkv, u16* __restrict__ y) {
  const int t = threadIdx.x;
  const int wv = t >> 6, lane = t & 63;
  int wid = blockIdx.x * 4 + wv;
  const int w = wid & (NB - 1); wid >>= 10;
  const int head = wid & 3; wid >>= 2;
  const int b = wid & 7; wid >>= 3;
  const int dil = wid;

  const int colq = dil * 256 + head * 64 + lane;
  float q[3], k[3], v[3];
  #pragma unroll
  for (int i = 0; i < 3; ++i) {
    const size_t row = (size_t)(b * Nn + i * NB + w) * C3;
    q[i] = bf2f(qkv[row + colq]);
    k[i] = bf2f(qkv[row + 768 + colq]);
    v[i] = bf2f(qkv[row + 1536 + colq]);
  }

  float s[3][3];
  #pragma unroll
  for (int i = 0; i < 3; ++i)
    #pragma unroll
    for (int j = 0; j < 3; ++j) {
      float p = q[i] * k[j];
      #pragma unroll
      for (int off = 32; off > 0; off >>= 1)
        p += __shfl_xor(p, off, 64);
      s[i][j] = p * 0.125f;
    }

  #pragma unroll
  for (int i = 0; i < 3; ++i) {
    const float mx = fmaxf(fmaxf(s[i][0], s[i][1]), s[i][2]);
    const float e0 = __expf(s[i][0] - mx);
    const float e1 = __expf(s[i][1] - mx);
    const float e2 = __expf(s[i][2] - mx);
    const float inv = 1.0f / (e0 + e1 + e2);
    const float o = (e0 * v[0] + e1 * v[1] + e2 * v[2]) * inv;
    const int linear = head * 192 + i * 64 + lane;
    const int nout = w * 3 + (linear >> 8);
    const int dd = linear & 255;
    y[(size_t)(b * Nn + nout) * Cc + dil * 256 + dd] = f2bf_rne(o);
  }
}

extern "C" void kernel_launch(void* const* d_in, const int* in_sizes, int n_in,
                              void* d_out, int out_size, void* d_ws, size_t ws_size,
                              hipStream_t stream) {
  const float* x      = (const float*)d_in[0];
  const float* qkv_w  = (const float*)d_in[1];
  const float* proj_w = (const float*)d_in[2];
  const float* proj_b = (const float*)d_in[3];

  char* ws = (char*)d_ws;
  u16* wq_b = (u16*)(ws);                      //  2304*768 bf16
  u16* wp_b = (u16*)(ws + 3538944);            //   768*768 bf16
  u16* xb   = (u16*)(ws + 4718592);            // 24576*768 bf16 (reused as yb)
  u16* qkvb = (u16*)(ws + 42467328);           // 24576*2304 bf16
  u16* yb   = xb;

  cvt_all<<<2048, 256, 0, stream>>>((const float4*)x, (const float4*)qkv_w,
                                    (const float4*)proj_w, (ushort4*)xb,
                                    (ushort4*)wq_b, (ushort4*)wp_b);

  // GEMM1: qkvb[M,2304] = xb[M,768] @ wq_b[2304,768]^T   (864 blocks, 16 waves)
  gemm256w16<false><<<(Mr / 256) * (C3 / 256), 1024, 0, stream>>>(xb, wq_b, qkvb, nullptr, C3, Cc);

  // attention: 98304 windows, 4 per block
  attn_local<<<(3 * 8 * 4 * 1024) / 4, 256, 0, stream>>>(qkvb, yb);

  // GEMM2: out[M,768] = yb[M,768] @ wp_b[768,768]^T + proj_b   (1152 blocks)
  gemm128<true><<<(Mr / 128) * (Cc / 128), 256, 0, stream>>>(yb, wp_b, d_out, proj_b, Cc, Cc);
}

// Round 8
// 253.121 us; speedup vs baseline: 1.0703x; 1.0083x over previous
//
#include <hip/hip_runtime.h>
#include <stdint.h>

#define DEVFN __device__ __forceinline__

typedef unsigned short u16;
typedef __bf16 bf16_t;
typedef bf16_t bf16x8 __attribute__((ext_vector_type(8)));
typedef float  f32x4  __attribute__((ext_vector_type(4)));

static constexpr int Bb = 8, Nn = 3072, Cc = 768;
static constexpr int Mr = Bb * Nn;      // 24576 rows
static constexpr int C3 = 3 * Cc;       // 2304
static constexpr int NB = 1024;         // dilation stride

DEVFN u16 f2bf_rne(float f) {
  uint32_t u = __builtin_bit_cast(uint32_t, f);
  u += 0x7FFFu + ((u >> 16) & 1u);
  return (u16)(u >> 16);
}
DEVFN float bf2f(u16 v) {
  uint32_t u = ((uint32_t)v) << 16;
  return __builtin_bit_cast(float, u);
}

// ---------------- fused f32 -> bf16 converts ----------------
__global__ void cvt_all(const float4* __restrict__ x, const float4* __restrict__ wq,
                        const float4* __restrict__ wp, ushort4* __restrict__ xb,
                        ushort4* __restrict__ wqb, ushort4* __restrict__ wpb) {
  const int NX = Mr * Cc / 4, NQ = C3 * Cc / 4, NP = Cc * Cc / 4;
  int i = blockIdx.x * blockDim.x + threadIdx.x;
  const int stride = gridDim.x * blockDim.x;
  for (; i < NX + NQ + NP; i += stride) {
    const float4* src; ushort4* dst; int j;
    if (i < NX)           { src = x;  dst = xb;  j = i; }
    else if (i < NX + NQ) { src = wq; dst = wqb; j = i - NX; }
    else                  { src = wp; dst = wpb; j = i - NX - NQ; }
    float4 v = src[j];
    ushort4 o;
    o.x = f2bf_rne(v.x); o.y = f2bf_rne(v.y);
    o.z = f2bf_rne(v.z); o.w = f2bf_rne(v.w);
    dst[j] = o;
  }
}

// ---------------- async global->LDS, 16B per lane ----------------
DEVFN void gload_lds16(const void* g, void* l) {
  __builtin_amdgcn_global_load_lds(
      (const __attribute__((address_space(1))) uint32_t*)g,
      (__attribute__((address_space(3))) uint32_t*)l,
      16, 0, 0);
}

// =====================================================================
// 256x256 bf16 NT GEMM — m201-faithful 8-phase schedule.
// 8 waves (2M x 4N), wave tile 128x64. BK=64 K-tile, double-buffered:
// LDS = 2 bufs x (A 256x64 + B 256x64) x 2B = 128 KiB.
// Per K-tile: 4 quadrant-phases, each {ds_read subtile || stage -> barrier
// -> lgkmcnt(0) -> sched_barrier -> setprio(1) -> 16 MFMA -> setprio(0)
// -> barrier}. Reads/tile = 24 b128 (12/4/8/0: A-half + both B-halves
// held in regs across phases). Staging: 8 gloads bunched in ph0/ph1 into
// the other buffer; single vmcnt(0) at ph3 (~2 phases of latency cover).
// Swizzle (128B rows): LDS(r, slot s) holds global(r, s ^ (r&7));
// 16-lane beat -> 8 slots x 2 rows = all 32 banks 2x = conflict-free.
// Operand-swapped MFMA (verified R6): lane's 4 acc regs = 4 consecutive
// output cols -> vectorized stores.
// =====================================================================
template <bool OUT_F32>
__global__ __launch_bounds__(512, 2)
void gemm8ph(const u16* __restrict__ A, const u16* __restrict__ Bw,
             void* __restrict__ Cout, const float* __restrict__ bias,
             int Ndim, int K) {
  __shared__ char lds[131072];

  const int nTn = Ndim >> 8;
  const int nwg = gridDim.x;
  const int bid = blockIdx.x;
  const int wgid = (bid & 7) * (nwg >> 3) + (bid >> 3);   // XCD swizzle (nwg%8==0)
  const int tm = wgid / nTn, tn = wgid % nTn;

  const int t = threadIdx.x;
  const int l = t & 63;
  const int w = t >> 6;          // wave 0..7
  const int wrow = w >> 2;       // M half (0/1): rows [wrow*128, +128)
  const int wcol = w & 3;        // N quarter (0..3): cols [wcol*64, +64)

  const int NT = K >> 6;         // K-tiles of 64 (12)

  // ---- staging addressing (thread t, gload g covers 16B chunk g*512+t) ----
  // chunk c: row = c>>3 (= g*64 + (t>>3)), slot = c&7 (= t&7).
  // source col slot pre-swizzled: (t&7) ^ (row&7); row&7 = (t>>3)&7.
  const int trow = t >> 3;                      // 0..63
  const int sslot = (t & 7) ^ (trow & 7);
  const u16* sA = A  + (size_t)(tm * 256 + trow) * K + sslot * 8;
  const u16* sB = Bw + (size_t)(tn * 256 + trow) * K + sslot * 8;

  // ---- ds_read per-lane offsets (swizzled), ks = K-half of tile ----
  // frag read: row = base16 + (l&15), byte = row*128 + ((ks*4+(l>>4)) ^ (l&7))*16
  const int lo0 = (l & 15) * 128 + ((     (l >> 4)) ^ (l & 7)) * 16;
  const int lo1 = (l & 15) * 128 + ((4 + (l >> 4)) ^ (l & 7)) * 16;

  f32x4 acc[8][4];
  #pragma unroll
  for (int m = 0; m < 8; ++m)
    #pragma unroll
    for (int n = 0; n < 4; ++n)
      acc[m][n] = f32x4{0.f, 0.f, 0.f, 0.f};

  bf16x8 af[4][2];     // current A-half frags (4 m-frags x 2 ks)
  bf16x8 b0[2][2];     // B-half 0 frags (fn 0,1)
  bf16x8 b1[2][2];     // B-half 1 frags (fn 2,3)

#define STAGE2(DST, G, TKO)                                                   \
  do {                                                                        \
    gload_lds16(sA + (size_t)(G) * 64 * K + (TKO), (DST) + ((G) * 512 + t) * 16);          \
    gload_lds16(sB + (size_t)(G) * 64 * K + (TKO), (DST) + 32768 + ((G) * 512 + t) * 16);  \
  } while (0)

#define READ_A(AB, HALF)                                                      \
  do {                                                                        \
    _Pragma("unroll")                                                         \
    for (int fm = 0; fm < 4; ++fm) {                                          \
      af[fm][0] = *reinterpret_cast<const bf16x8*>(                           \
          (AB) + wrow * 16384 + ((HALF) * 4 + fm) * 2048 + lo0);              \
      af[fm][1] = *reinterpret_cast<const bf16x8*>(                           \
          (AB) + wrow * 16384 + ((HALF) * 4 + fm) * 2048 + lo1);              \
    }                                                                         \
  } while (0)

#define READ_B(BB, HALF, DST)                                                 \
  do {                                                                        \
    _Pragma("unroll")                                                         \
    for (int fn = 0; fn < 2; ++fn) {                                          \
      DST[fn][0] = *reinterpret_cast<const bf16x8*>(                          \
          (BB) + wcol * 8192 + ((HALF) * 2 + fn) * 2048 + lo0);               \
      DST[fn][1] = *reinterpret_cast<const bf16x8*>(                          \
          (BB) + wcol * 8192 + ((HALF) * 2 + fn) * 2048 + lo1);               \
    }                                                                         \
  } while (0)

#define MFMA_Q(MHALF, BFR, NB)                                                \
  do {                                                                        \
    __builtin_amdgcn_s_setprio(1);                                            \
    _Pragma("unroll")                                                         \
    for (int fm = 0; fm < 4; ++fm)                                            \
      _Pragma("unroll")                                                       \
      for (int fn = 0; fn < 2; ++fn) {                                        \
        acc[(MHALF) * 4 + fm][(NB) + fn] =                                    \
            __builtin_amdgcn_mfma_f32_16x16x32_bf16(BFR[fn][0], af[fm][0],    \
                acc[(MHALF) * 4 + fm][(NB) + fn], 0, 0, 0);                   \
        acc[(MHALF) * 4 + fm][(NB) + fn] =                                    \
            __builtin_amdgcn_mfma_f32_16x16x32_bf16(BFR[fn][1], af[fm][1],    \
                acc[(MHALF) * 4 + fm][(NB) + fn], 0, 0, 0);                   \
      }                                                                       \
    __builtin_amdgcn_s_setprio(0);                                            \
  } while (0)

#define SYNC_PRE_MFMA()                                                       \
  do {                                                                        \
    __builtin_amdgcn_s_barrier();                                             \
    asm volatile("s_waitcnt lgkmcnt(0)" ::: "memory");                        \
    __builtin_amdgcn_sched_barrier(0);                                        \
  } while (0)

  // prologue: stage tile 0 into buf 0, drain, sync
  #pragma unroll
  for (int g = 0; g < 4; ++g) STAGE2(lds, g, 0);
  asm volatile("s_waitcnt vmcnt(0)" ::: "memory");
  __builtin_amdgcn_s_barrier();

  for (int tt = 0; tt < NT; ++tt) {
    const char* Ab = lds + (tt & 1) * 65536;
    const char* Bbuf = Ab + 32768;
    char* nbuf = lds + ((tt + 1) & 1) * 65536;
    const bool pf = (tt + 1 < NT);
    const size_t tko = (size_t)(tt + 1) * 64;

    // ph0: Q00 — read A-half0 (8) + B-half0 (4); stage g0,g1
    READ_A(Ab, 0);
    READ_B(Bbuf, 0, b0);
    if (pf) { STAGE2(nbuf, 0, tko); STAGE2(nbuf, 1, tko); }
    SYNC_PRE_MFMA();
    MFMA_Q(0, b0, 0);
    __builtin_amdgcn_s_barrier();

    // ph1: Q01 — read B-half1 (4); stage g2,g3
    READ_B(Bbuf, 1, b1);
    if (pf) { STAGE2(nbuf, 2, tko); STAGE2(nbuf, 3, tko); }
    SYNC_PRE_MFMA();
    MFMA_Q(0, b1, 2);
    __builtin_amdgcn_s_barrier();

    // ph2: Q11 — read A-half1 (8)
    READ_A(Ab, 1);
    SYNC_PRE_MFMA();
    MFMA_Q(1, b1, 2);
    __builtin_amdgcn_s_barrier();

    // ph3: Q10 — no reads; next tile's staging landed (issued >=2 phases ago)
    if (pf) asm volatile("s_waitcnt vmcnt(0)" ::: "memory");
    __builtin_amdgcn_s_barrier();
    MFMA_Q(1, b0, 0);
    __builtin_amdgcn_s_barrier();
  }
#undef STAGE2
#undef READ_A
#undef READ_B
#undef MFMA_Q
#undef SYNC_PRE_MFMA

  // epilogue (operand-swapped layout, verified R6): lane l, frag (fm,fn),
  // reg j -> C[fm*16 + (l&15)][fn*16 + (l>>4)*4 + j]
  const int grow0 = tm * 256 + wrow * 128 + (l & 15);
  const int gcol0 = tn * 256 + wcol * 64 + (l >> 4) * 4;
  #pragma unroll
  for (int fm = 0; fm < 8; ++fm) {
    const int row = grow0 + fm * 16;
    #pragma unroll
    for (int fn = 0; fn < 4; ++fn) {
      const int col = gcol0 + fn * 16;
      if constexpr (OUT_F32) {
        float* O = (float*)Cout;
        const float4 bv = *reinterpret_cast<const float4*>(&bias[col]);
        float4 o;
        o.x = acc[fm][fn][0] + bv.x;
        o.y = acc[fm][fn][1] + bv.y;
        o.z = acc[fm][fn][2] + bv.z;
        o.w = acc[fm][fn][3] + bv.w;
        *reinterpret_cast<float4*>(&O[(size_t)row * Ndim + col]) = o;
      } else {
        u16* O = (u16*)Cout;
        ushort4 o;
        o.x = f2bf_rne(acc[fm][fn][0]);
        o.y = f2bf_rne(acc[fm][fn][1]);
        o.z = f2bf_rne(acc[fm][fn][2]);
        o.w = f2bf_rne(acc[fm][fn][3]);
        *reinterpret_cast<ushort4*>(&O[(size_t)row * Ndim + col]) = o;
      }
    }
  }
}

// =====================================================================
// 128x128 bf16 NT GEMM, 4 waves, 3-slot ring, 3 blocks/CU (R6, verified).
// =====================================================================
template <bool OUT_F32>
__global__ __launch_bounds__(256, 3)
void gemm128(const u16* __restrict__ A, const u16* __restrict__ Bw,
             void* __restrict__ Cout, const float* __restrict__ bias,
             int Ndim, int K) {
  __shared__ u16 As[3][128 * 32];
  __shared__ u16 Bs[3][128 * 32];

  const int nTn = Ndim >> 7;
  const int nwg = gridDim.x;
  const int bid = blockIdx.x;
  const int wgid = (bid & 7) * (nwg >> 3) + (bid >> 3);
  const int tm = wgid / nTn, tn = wgid % nTn;

  const int t = threadIdx.x;
  const int l = t & 63;
  const int w = t >> 6;
  const int wrh = w >> 1;
  const int wch = w & 1;
  const int lr = l & 15;

  const int NPH = K >> 5;

  const int srow = t >> 2;
  const int scol = 8 * ((t & 3) ^ ((srow >> 1) & 3));
  const u16* pA0 = A  + (size_t)(tm * 128 +      srow) * K + scol;
  const u16* pA1 = A  + (size_t)(tm * 128 + 64 + srow) * K + scol;
  const u16* pB0 = Bw + (size_t)(tn * 128 +      srow) * K + scol;
  const u16* pB1 = Bw + (size_t)(tn * 128 + 64 + srow) * K + scol;

  const int lane_off = lr * 64 + (((l >> 4) * 16) ^ (((lr >> 1) & 3) << 4));

  f32x4 acc[4][4];
  #pragma unroll
  for (int m = 0; m < 4; ++m)
    #pragma unroll
    for (int n = 0; n < 4; ++n)
      acc[m][n] = f32x4{0.f, 0.f, 0.f, 0.f};

  #pragma unroll
  for (int q = 0; q < 2; ++q) {
    const size_t ko = (size_t)q * 32;
    gload_lds16(pA0 + ko, &As[q][(size_t)t * 8]);
    gload_lds16(pA1 + ko, &As[q][(size_t)(t + 256) * 8]);
    gload_lds16(pB0 + ko, &Bs[q][(size_t)t * 8]);
    gload_lds16(pB1 + ko, &Bs[q][(size_t)(t + 256) * 8]);
  }

  int slot = 0;
  for (int p = 0; p < NPH; ++p) {
    if (p + 2 < NPH) {
      int ps = slot + 2; if (ps >= 3) ps -= 3;
      const size_t ko = (size_t)(p + 2) * 32;
      gload_lds16(pA0 + ko, &As[ps][(size_t)t * 8]);
      gload_lds16(pA1 + ko, &As[ps][(size_t)(t + 256) * 8]);
      gload_lds16(pB0 + ko, &Bs[ps][(size_t)t * 8]);
      gload_lds16(pB1 + ko, &Bs[ps][(size_t)(t + 256) * 8]);
      asm volatile("s_waitcnt vmcnt(8)" ::: "memory");
    } else if (p + 2 == NPH) {
      asm volatile("s_waitcnt vmcnt(4)" ::: "memory");
    } else {
      asm volatile("s_waitcnt vmcnt(0)" ::: "memory");
    }
    __builtin_amdgcn_s_barrier();

    const char* ab = (const char*)As[slot] + wrh * 4096 + lane_off;
    const char* bb = (const char*)Bs[slot] + wch * 4096 + lane_off;
    bf16x8 af[4], bf[4];
    #pragma unroll
    for (int m = 0; m < 4; ++m)
      af[m] = *reinterpret_cast<const bf16x8*>(ab + m * 1024);
    #pragma unroll
    for (int n = 0; n < 4; ++n)
      bf[n] = *reinterpret_cast<const bf16x8*>(bb + n * 1024);

    __builtin_amdgcn_s_setprio(1);
    #pragma unroll
    for (int m = 0; m < 4; ++m)
      #pragma unroll
      for (int n = 0; n < 4; ++n)
        acc[m][n] = __builtin_amdgcn_mfma_f32_16x16x32_bf16(bf[n], af[m],
                                                            acc[m][n], 0, 0, 0);
    __builtin_amdgcn_s_setprio(0);
    __builtin_amdgcn_s_barrier();

    slot = (slot == 2) ? 0 : slot + 1;
  }

  const int grow0 = tm * 128 + wrh * 64 + lr;
  const int gcol0 = tn * 128 + wch * 64 + (l >> 4) * 4;
  #pragma unroll
  for (int m = 0; m < 4; ++m) {
    const int row = grow0 + m * 16;
    #pragma unroll
    for (int n = 0; n < 4; ++n) {
      const int col = gcol0 + n * 16;
      if constexpr (OUT_F32) {
        float* O = (float*)Cout;
        const float4 bv = *reinterpret_cast<const float4*>(&bias[col]);
        float4 o;
        o.x = acc[m][n][0] + bv.x;
        o.y = acc[m][n][1] + bv.y;
        o.z = acc[m][n][2] + bv.z;
        o.w = acc[m][n][3] + bv.w;
        *reinterpret_cast<float4*>(&O[(size_t)row * Ndim + col]) = o;
      } else {
        u16* O = (u16*)Cout;
        ushort4 o;
        o.x = f2bf_rne(acc[m][n][0]);
        o.y = f2bf_rne(acc[m][n][1]);
        o.z = f2bf_rne(acc[m][n][2]);
        o.w = f2bf_rne(acc[m][n][3]);
        *reinterpret_cast<ushort4*>(&O[(size_t)row * Ndim + col]) = o;
      }
    }
  }
}

// ---------------- local 3x3 dilated attention, one wave per window ----------------
__global__ __launch_bounds__(256)
void attn_local(const u16* __restrict__ qkv, u16* __restrict__ y) {
  const int t = threadIdx.x;
  const int wv = t >> 6, lane = t & 63;
  int wid = blockIdx.x * 4 + wv;
  const int w = wid & (NB - 1); wid >>= 10;
  const int head = wid & 3; wid >>= 2;
  const int b = wid & 7; wid >>= 3;
  const int dil = wid;

  const int colq = dil * 256 + head * 64 + lane;
  float q[3], k[3], v[3];
  #pragma unroll
  for (int i = 0; i < 3; ++i) {
    const size_t row = (size_t)(b * Nn + i * NB + w) * C3;
    q[i] = bf2f(qkv[row + colq]);
    k[i] = bf2f(qkv[row + 768 + colq]);
    v[i] = bf2f(qkv[row + 1536 + colq]);
  }

  float s[3][3];
  #pragma unroll
  for (int i = 0; i < 3; ++i)
    #pragma unroll
    for (int j = 0; j < 3; ++j) {
      float p = q[i] * k[j];
      #pragma unroll
      for (int off = 32; off > 0; off >>= 1)
        p += __shfl_xor(p, off, 64);
      s[i][j] = p * 0.125f;
    }

  #pragma unroll
  for (int i = 0; i < 3; ++i) {
    const float mx = fmaxf(fmaxf(s[i][0], s[i][1]), s[i][2]);
    const float e0 = __expf(s[i][0] - mx);
    const float e1 = __expf(s[i][1] - mx);
    const float e2 = __expf(s[i][2] - mx);
    const float inv = 1.0f / (e0 + e1 + e2);
    const float o = (e0 * v[0] + e1 * v[1] + e2 * v[2]) * inv;
    const int linear = head * 192 + i * 64 + lane;
    const int nout = w * 3 + (linear >> 8);
    const int dd = linear & 255;
    y[(size_t)(b * Nn + nout) * Cc + dil * 256 + dd] = f2bf_rne(o);
  }
}

extern "C" void kernel_launch(void* const* d_in, const int* in_sizes, int n_in,
                              void* d_out, int out_size, void* d_ws, size_t ws_size,
                              hipStream_t stream) {
  const float* x      = (const float*)d_in[0];
  const float* qkv_w  = (const float*)d_in[1];
  const float* proj_w = (const float*)d_in[2];
  const float* proj_b = (const float*)d_in[3];

  char* ws = (char*)d_ws;
  u16* wq_b = (u16*)(ws);                      //  2304*768 bf16
  u16* wp_b = (u16*)(ws + 3538944);            //   768*768 bf16
  u16* xb   = (u16*)(ws + 4718592);            // 24576*768 bf16 (reused as yb)
  u16* qkvb = (u16*)(ws + 42467328);           // 24576*2304 bf16
  u16* yb   = xb;

  cvt_all<<<2048, 256, 0, stream>>>((const float4*)x, (const float4*)qkv_w,
                                    (const float4*)proj_w, (ushort4*)xb,
                                    (ushort4*)wq_b, (ushort4*)wp_b);

  // GEMM1: qkvb[M,2304] = xb[M,768] @ wq_b[2304,768]^T   (864 blocks, 8 waves)
  gemm8ph<false><<<(Mr / 256) * (C3 / 256), 512, 0, stream>>>(xb, wq_b, qkvb, nullptr, C3, Cc);

  // attention: 98304 windows, 4 per block
  attn_local<<<(3 * 8 * 4 * 1024) / 4, 256, 0, stream>>>(qkvb, yb);

  // GEMM2: out[M,768] = yb[M,768] @ wp_b[768,768]^T + proj_b   (1152 blocks)
  gemm128<true><<<(Mr / 128) * (Cc / 128), 256, 0, stream>>>(yb, wp_b, d_out, proj_b, Cc, Cc);
}

// Round 9
// 204.410 us; speedup vs baseline: 1.3254x; 1.2383x over previous
//
#include <hip/hip_runtime.h>
#include <stdint.h>

#define DEVFN __device__ __forceinline__

typedef unsigned short u16;
typedef __bf16 bf16_t;
typedef bf16_t bf16x8 __attribute__((ext_vector_type(8)));
typedef float  f32x4  __attribute__((ext_vector_type(4)));

static constexpr int Bb = 8, Nn = 3072, Cc = 768;
static constexpr int Mr = Bb * Nn;      // 24576 rows
static constexpr int C3 = 3 * Cc;       // 2304
static constexpr int NB = 1024;         // dilation stride

DEVFN u16 f2bf_rne(float f) {
  uint32_t u = __builtin_bit_cast(uint32_t, f);
  u += 0x7FFFu + ((u >> 16) & 1u);
  return (u16)(u >> 16);
}
DEVFN float bf2f(u16 v) {
  uint32_t u = ((uint32_t)v) << 16;
  return __builtin_bit_cast(float, u);
}

// ---------------- fused f32 -> bf16 converts ----------------
__global__ void cvt_all(const float4* __restrict__ x, const float4* __restrict__ wq,
                        const float4* __restrict__ wp, ushort4* __restrict__ xb,
                        ushort4* __restrict__ wqb, ushort4* __restrict__ wpb) {
  const int NX = Mr * Cc / 4, NQ = C3 * Cc / 4, NP = Cc * Cc / 4;
  int i = blockIdx.x * blockDim.x + threadIdx.x;
  const int stride = gridDim.x * blockDim.x;
  for (; i < NX + NQ + NP; i += stride) {
    const float4* src; ushort4* dst; int j;
    if (i < NX)           { src = x;  dst = xb;  j = i; }
    else if (i < NX + NQ) { src = wq; dst = wqb; j = i - NX; }
    else                  { src = wp; dst = wpb; j = i - NX - NQ; }
    float4 v = src[j];
    ushort4 o;
    o.x = f2bf_rne(v.x); o.y = f2bf_rne(v.y);
    o.z = f2bf_rne(v.z); o.w = f2bf_rne(v.w);
    dst[j] = o;
  }
}

// ---------------- async global->LDS, 16B per lane ----------------
DEVFN void gload_lds16(const void* g, void* l) {
  __builtin_amdgcn_global_load_lds(
      (const __attribute__((address_space(1))) uint32_t*)g,
      (__attribute__((address_space(3))) uint32_t*)l,
      16, 0, 0);
}

// =====================================================================
// 256x256 bf16 NT GEMM — R2 VERBATIM (empirical best: 108.6 us GEMM1).
// 8 waves, 4-slot K=32-slice ring, counted vmcnt(8), 1 barrier/slice.
// Ledger note: 5 "improvements" on this (swizzle-fix, operand-swap,
// sub-phases, 3blk/CU 128-tile, 16-wave, BK=64 8-phase) all regressed
// (R3-R8: 117-141 us). Do not touch without within-round A/B.
// =====================================================================
template <bool OUT_F32>
__global__ __launch_bounds__(512, 2)
void gemm256(const u16* __restrict__ A, const u16* __restrict__ Bw,
             void* __restrict__ Cout, const float* __restrict__ bias,
             int Ndim, int K) {
  constexpr int SLOT = 32768;
  __shared__ char lds[4 * SLOT];   // 128 KiB

  const int nTn = Ndim >> 8;
  const int nwg = gridDim.x;
  const int bid = blockIdx.x;
  const int wgid = (bid & 7) * (nwg >> 3) + (bid >> 3);   // XCD swizzle (nwg%8==0)
  const int tm = wgid / nTn, tn = wgid % nTn;

  const int t = threadIdx.x;
  const int l = t & 63;
  const int w = t >> 6;
  const int wr = w >> 2;         // M half of tile
  const int wcq = w & 3;         // N quarter of tile
  const int lr = l & 15;

  const int NPH = K >> 5;

  const int srow = l >> 2;
  const int scol = 8 * ((l & 3) ^ (srow & 3));
  const u16* pA0 = A  + (size_t)(tm * 256 +       w * 16 + srow) * K + scol;
  const u16* pA1 = A  + (size_t)(tm * 256 + 128 + w * 16 + srow) * K + scol;
  const u16* pB0 = Bw + (size_t)(tn * 256 +       w * 16 + srow) * K + scol;
  const u16* pB1 = Bw + (size_t)(tn * 256 + 128 + w * 16 + srow) * K + scol;

  const int lane_off = lr * 64 + (((l >> 4) * 16) ^ ((lr & 3) << 4));

  f32x4 acc[8][4];
  #pragma unroll
  for (int m = 0; m < 8; ++m)
    #pragma unroll
    for (int n = 0; n < 4; ++n)
      acc[m][n] = f32x4{0.f, 0.f, 0.f, 0.f};

  #pragma unroll
  for (int q = 0; q < 3; ++q) {
    char* dA = &lds[q * SLOT + w * 1024];
    char* dB = &lds[q * SLOT + 16384 + w * 1024];
    const size_t ko = (size_t)q * 32;
    gload_lds16(pA0 + ko, dA);
    gload_lds16(pA1 + ko, dA + 8192);
    gload_lds16(pB0 + ko, dB);
    gload_lds16(pB1 + ko, dB + 8192);
  }

#define GPHASE(VMSTR, PF_COND)                                                \
  do {                                                                        \
    asm volatile(VMSTR ::: "memory");                                         \
    __builtin_amdgcn_s_barrier();                                             \
    asm volatile("" ::: "memory");                                            \
    const char* ab = &lds[(p & 3) * SLOT] + wr * 8192 + lane_off;             \
    const char* bb = &lds[(p & 3) * SLOT + 16384] + wcq * 4096 + lane_off;    \
    bf16x8 af[8], bf[4];                                                      \
    _Pragma("unroll")                                                         \
    for (int m = 0; m < 8; ++m)                                               \
      af[m] = *reinterpret_cast<const bf16x8*>(ab + m * 1024);                \
    _Pragma("unroll")                                                         \
    for (int n = 0; n < 4; ++n)                                               \
      bf[n] = *reinterpret_cast<const bf16x8*>(bb + n * 1024);                \
    if (PF_COND) {                                                            \
      const int ps = (p + 3) & 3;                                             \
      char* dA = &lds[ps * SLOT + w * 1024];                                  \
      char* dB = &lds[ps * SLOT + 16384 + w * 1024];                          \
      const size_t ko = (size_t)(p + 3) * 32;                                 \
      gload_lds16(pA0 + ko, dA);                                              \
      gload_lds16(pA1 + ko, dA + 8192);                                       \
      gload_lds16(pB0 + ko, dB);                                              \
      gload_lds16(pB1 + ko, dB + 8192);                                       \
    }                                                                         \
    __builtin_amdgcn_s_setprio(1);                                            \
    _Pragma("unroll")                                                         \
    for (int m = 0; m < 8; ++m)                                               \
      _Pragma("unroll")                                                       \
      for (int n = 0; n < 4; ++n)                                             \
        acc[m][n] = __builtin_amdgcn_mfma_f32_16x16x32_bf16(af[m], bf[n],     \
                                                            acc[m][n], 0,0,0);\
    __builtin_amdgcn_s_setprio(0);                                            \
    asm volatile("" ::: "memory");                                            \
  } while (0)

  int p = 0;
  for (; p < NPH - 2; ++p) GPHASE("s_waitcnt vmcnt(8)", (p + 3 < NPH));
  GPHASE("s_waitcnt vmcnt(4)", false); ++p;
  GPHASE("s_waitcnt vmcnt(0)", false); ++p;
#undef GPHASE

  // epilogue: C/D layout col=lane&15, row=(lane>>4)*4+j
  const int rbase = tm * 256 + wr * 128 + (l >> 4) * 4;
  #pragma unroll
  for (int m = 0; m < 8; ++m) {
    #pragma unroll
    for (int n = 0; n < 4; ++n) {
      const int col = tn * 256 + wcq * 64 + n * 16 + lr;
      const int row0 = rbase + m * 16;
      if constexpr (OUT_F32) {
        float* O = (float*)Cout;
        const float bv = bias[col];
        #pragma unroll
        for (int j = 0; j < 4; ++j)
          O[(size_t)(row0 + j) * Ndim + col] = acc[m][n][j] + bv;
      } else {
        u16* O = (u16*)Cout;
        #pragma unroll
        for (int j = 0; j < 4; ++j)
          O[(size_t)(row0 + j) * Ndim + col] = f2bf_rne(acc[m][n][j]);
      }
    }
  }
}

// =====================================================================
// 128x128 bf16 NT GEMM, 4 waves, 3-slot ring, 3 blocks/CU (R6 verbatim).
// Used for GEMM2: 1152 blocks @ 3/CU beats 288 @ 1/CU by ~13 us.
// =====================================================================
template <bool OUT_F32>
__global__ __launch_bounds__(256, 3)
void gemm128(const u16* __restrict__ A, const u16* __restrict__ Bw,
             void* __restrict__ Cout, const float* __restrict__ bias,
             int Ndim, int K) {
  __shared__ u16 As[3][128 * 32];
  __shared__ u16 Bs[3][128 * 32];

  const int nTn = Ndim >> 7;
  const int nwg = gridDim.x;
  const int bid = blockIdx.x;
  const int wgid = (bid & 7) * (nwg >> 3) + (bid >> 3);
  const int tm = wgid / nTn, tn = wgid % nTn;

  const int t = threadIdx.x;
  const int l = t & 63;
  const int w = t >> 6;
  const int wrh = w >> 1;
  const int wch = w & 1;
  const int lr = l & 15;

  const int NPH = K >> 5;

  const int srow = t >> 2;
  const int scol = 8 * ((t & 3) ^ ((srow >> 1) & 3));
  const u16* pA0 = A  + (size_t)(tm * 128 +      srow) * K + scol;
  const u16* pA1 = A  + (size_t)(tm * 128 + 64 + srow) * K + scol;
  const u16* pB0 = Bw + (size_t)(tn * 128 +      srow) * K + scol;
  const u16* pB1 = Bw + (size_t)(tn * 128 + 64 + srow) * K + scol;

  const int lane_off = lr * 64 + (((l >> 4) * 16) ^ (((lr >> 1) & 3) << 4));

  f32x4 acc[4][4];
  #pragma unroll
  for (int m = 0; m < 4; ++m)
    #pragma unroll
    for (int n = 0; n < 4; ++n)
      acc[m][n] = f32x4{0.f, 0.f, 0.f, 0.f};

  #pragma unroll
  for (int q = 0; q < 2; ++q) {
    const size_t ko = (size_t)q * 32;
    gload_lds16(pA0 + ko, &As[q][(size_t)t * 8]);
    gload_lds16(pA1 + ko, &As[q][(size_t)(t + 256) * 8]);
    gload_lds16(pB0 + ko, &Bs[q][(size_t)t * 8]);
    gload_lds16(pB1 + ko, &Bs[q][(size_t)(t + 256) * 8]);
  }

  int slot = 0;
  for (int p = 0; p < NPH; ++p) {
    if (p + 2 < NPH) {
      int ps = slot + 2; if (ps >= 3) ps -= 3;
      const size_t ko = (size_t)(p + 2) * 32;
      gload_lds16(pA0 + ko, &As[ps][(size_t)t * 8]);
      gload_lds16(pA1 + ko, &As[ps][(size_t)(t + 256) * 8]);
      gload_lds16(pB0 + ko, &Bs[ps][(size_t)t * 8]);
      gload_lds16(pB1 + ko, &Bs[ps][(size_t)(t + 256) * 8]);
      asm volatile("s_waitcnt vmcnt(8)" ::: "memory");
    } else if (p + 2 == NPH) {
      asm volatile("s_waitcnt vmcnt(4)" ::: "memory");
    } else {
      asm volatile("s_waitcnt vmcnt(0)" ::: "memory");
    }
    __builtin_amdgcn_s_barrier();

    const char* ab = (const char*)As[slot] + wrh * 4096 + lane_off;
    const char* bb = (const char*)Bs[slot] + wch * 4096 + lane_off;
    bf16x8 af[4], bf[4];
    #pragma unroll
    for (int m = 0; m < 4; ++m)
      af[m] = *reinterpret_cast<const bf16x8*>(ab + m * 1024);
    #pragma unroll
    for (int n = 0; n < 4; ++n)
      bf[n] = *reinterpret_cast<const bf16x8*>(bb + n * 1024);

    __builtin_amdgcn_s_setprio(1);
    #pragma unroll
    for (int m = 0; m < 4; ++m)
      #pragma unroll
      for (int n = 0; n < 4; ++n)
        acc[m][n] = __builtin_amdgcn_mfma_f32_16x16x32_bf16(bf[n], af[m],
                                                            acc[m][n], 0, 0, 0);
    __builtin_amdgcn_s_setprio(0);
    __builtin_amdgcn_s_barrier();

    slot = (slot == 2) ? 0 : slot + 1;
  }

  const int grow0 = tm * 128 + wrh * 64 + lr;
  const int gcol0 = tn * 128 + wch * 64 + (l >> 4) * 4;
  #pragma unroll
  for (int m = 0; m < 4; ++m) {
    const int row = grow0 + m * 16;
    #pragma unroll
    for (int n = 0; n < 4; ++n) {
      const int col = gcol0 + n * 16;
      if constexpr (OUT_F32) {
        float* O = (float*)Cout;
        const float4 bv = *reinterpret_cast<const float4*>(&bias[col]);
        float4 o;
        o.x = acc[m][n][0] + bv.x;
        o.y = acc[m][n][1] + bv.y;
        o.z = acc[m][n][2] + bv.z;
        o.w = acc[m][n][3] + bv.w;
        *reinterpret_cast<float4*>(&O[(size_t)row * Ndim + col]) = o;
      } else {
        u16* O = (u16*)Cout;
        ushort4 o;
        o.x = f2bf_rne(acc[m][n][0]);
        o.y = f2bf_rne(acc[m][n][1]);
        o.z = f2bf_rne(acc[m][n][2]);
        o.w = f2bf_rne(acc[m][n][3]);
        *reinterpret_cast<ushort4*>(&O[(size_t)row * Ndim + col]) = o;
      }
    }
  }
}

// =====================================================================
// local 3x3 dilated attention, 4x-vectorized: one wave per (dil,b,w)
// handles ALL 4 heads. Lane l: head h=l>>4, dims hi=(l&15)*4+e (e=0..3),
// ushort4 loads (8B/lane) and stores. Dot reduce = shfl_xor 1,2,4,8
// within the 16-lane head group. 24576 waves (was 98304).
// =====================================================================
__global__ __launch_bounds__(256)
void attn_local4(const u16* __restrict__ qkv, u16* __restrict__ y) {
  const int t = threadIdx.x;
  const int l = t & 63;
  int wid = blockIdx.x * 4 + (t >> 6);      // [0, 3*8*1024)
  const int w = wid & (NB - 1); wid >>= 10;
  const int b = wid & 7; wid >>= 3;
  const int dil = wid;                      // 0..2

  const int colq = dil * 256 + l * 4;       // 4 consecutive dims, head l>>4
  float q[3][4], k[3][4], v[3][4];
  #pragma unroll
  for (int i = 0; i < 3; ++i) {
    const size_t row = (size_t)(b * Nn + i * NB + w) * C3;
    const ushort4 q4 = *reinterpret_cast<const ushort4*>(&qkv[row + colq]);
    const ushort4 k4 = *reinterpret_cast<const ushort4*>(&qkv[row + 768 + colq]);
    const ushort4 v4 = *reinterpret_cast<const ushort4*>(&qkv[row + 1536 + colq]);
    q[i][0] = bf2f(q4.x); q[i][1] = bf2f(q4.y); q[i][2] = bf2f(q4.z); q[i][3] = bf2f(q4.w);
    k[i][0] = bf2f(k4.x); k[i][1] = bf2f(k4.y); k[i][2] = bf2f(k4.z); k[i][3] = bf2f(k4.w);
    v[i][0] = bf2f(v4.x); v[i][1] = bf2f(v4.y); v[i][2] = bf2f(v4.z); v[i][3] = bf2f(v4.w);
  }

  // scores: per-lane 4-elem partial dot, reduce over the 16-lane head group
  float s[3][3];
  #pragma unroll
  for (int i = 0; i < 3; ++i)
    #pragma unroll
    for (int j = 0; j < 3; ++j) {
      float p = q[i][0] * k[j][0] + q[i][1] * k[j][1]
              + q[i][2] * k[j][2] + q[i][3] * k[j][3];
      p += __shfl_xor(p, 1, 64);
      p += __shfl_xor(p, 2, 64);
      p += __shfl_xor(p, 4, 64);
      p += __shfl_xor(p, 8, 64);
      s[i][j] = p * 0.125f;   // hd=64 -> scale 1/8
    }

  #pragma unroll
  for (int i = 0; i < 3; ++i) {
    const float mx = fmaxf(fmaxf(s[i][0], s[i][1]), s[i][2]);
    const float e0 = __expf(s[i][0] - mx);
    const float e1 = __expf(s[i][1] - mx);
    const float e2 = __expf(s[i][2] - mx);
    const float inv = 1.0f / (e0 + e1 + e2);
    ushort4 o4;
    u16* po = &o4.x;
    #pragma unroll
    for (int e = 0; e < 4; ++e)
      po[e] = f2bf_rne((e0 * v[0][e] + e1 * v[1][e] + e2 * v[2][e]) * inv);
    // linear = h*192 + i*64 + hi; base (e=0) mult of 4, never crosses 256
    const int linear = (l >> 4) * 192 + i * 64 + (l & 15) * 4;
    const int nout = w * 3 + (linear >> 8);
    const int dd = linear & 255;
    *reinterpret_cast<ushort4*>(
        &y[(size_t)(b * Nn + nout) * Cc + dil * 256 + dd]) = o4;
  }
}

extern "C" void kernel_launch(void* const* d_in, const int* in_sizes, int n_in,
                              void* d_out, int out_size, void* d_ws, size_t ws_size,
                              hipStream_t stream) {
  const float* x      = (const float*)d_in[0];
  const float* qkv_w  = (const float*)d_in[1];
  const float* proj_w = (const float*)d_in[2];
  const float* proj_b = (const float*)d_in[3];

  char* ws = (char*)d_ws;
  u16* wq_b = (u16*)(ws);                      //  2304*768 bf16
  u16* wp_b = (u16*)(ws + 3538944);            //   768*768 bf16
  u16* xb   = (u16*)(ws + 4718592);            // 24576*768 bf16 (reused as yb)
  u16* qkvb = (u16*)(ws + 42467328);           // 24576*2304 bf16
  u16* yb   = xb;

  cvt_all<<<2048, 256, 0, stream>>>((const float4*)x, (const float4*)qkv_w,
                                    (const float4*)proj_w, (ushort4*)xb,
                                    (ushort4*)wq_b, (ushort4*)wp_b);

  // GEMM1: qkvb[M,2304] = xb[M,768] @ wq_b[2304,768]^T   (864 blocks, R2 best)
  gemm256<false><<<(Mr / 256) * (C3 / 256), 512, 0, stream>>>(xb, wq_b, qkvb, nullptr, C3, Cc);

  // attention: 24576 wave-groups (4 heads each), 4 per block
  attn_local4<<<(3 * 8 * 1024) / 4, 256, 0, stream>>>(qkvb, yb);

  // GEMM2: out[M,768] = yb[M,768] @ wp_b[768,768]^T + proj_b   (1152 blocks)
  gemm128<true><<<(Mr / 128) * (Cc / 128), 256, 0, stream>>>(yb, wp_b, d_out, proj_b, Cc, Cc);
}

// Round 10
// 203.215 us; speedup vs baseline: 1.3332x; 1.0059x over previous
//
#include <hip/hip_runtime.h>
#include <stdint.h>

#define DEVFN __device__ __forceinline__

typedef unsigned short u16;
typedef __bf16 bf16_t;
typedef bf16_t bf16x8 __attribute__((ext_vector_type(8)));
typedef float  f32x4  __attribute__((ext_vector_type(4)));

static constexpr int Bb = 8, Nn = 3072, Cc = 768;
static constexpr int Mr = Bb * Nn;      // 24576 rows
static constexpr int C3 = 3 * Cc;       // 2304
static constexpr int NB = 1024;         // dilation stride

DEVFN u16 f2bf_rne(float f) {
  uint32_t u = __builtin_bit_cast(uint32_t, f);
  u += 0x7FFFu + ((u >> 16) & 1u);
  return (u16)(u >> 16);
}
DEVFN float bf2f(u16 v) {
  uint32_t u = ((uint32_t)v) << 16;
  return __builtin_bit_cast(float, u);
}

// ---------------- fused f32 -> bf16 converts ----------------
__global__ void cvt_all(const float4* __restrict__ x, const float4* __restrict__ wq,
                        const float4* __restrict__ wp, ushort4* __restrict__ xb,
                        ushort4* __restrict__ wqb, ushort4* __restrict__ wpb) {
  const int NX = Mr * Cc / 4, NQ = C3 * Cc / 4, NP = Cc * Cc / 4;
  int i = blockIdx.x * blockDim.x + threadIdx.x;
  const int stride = gridDim.x * blockDim.x;
  for (; i < NX + NQ + NP; i += stride) {
    const float4* src; ushort4* dst; int j;
    if (i < NX)           { src = x;  dst = xb;  j = i; }
    else if (i < NX + NQ) { src = wq; dst = wqb; j = i - NX; }
    else                  { src = wp; dst = wpb; j = i - NX - NQ; }
    float4 v = src[j];
    ushort4 o;
    o.x = f2bf_rne(v.x); o.y = f2bf_rne(v.y);
    o.z = f2bf_rne(v.z); o.w = f2bf_rne(v.w);
    dst[j] = o;
  }
}

// ---------------- async global->LDS, 16B per lane ----------------
DEVFN void gload_lds16(const void* g, void* l) {
  __builtin_amdgcn_global_load_lds(
      (const __attribute__((address_space(1))) uint32_t*)g,
      (__attribute__((address_space(3))) uint32_t*)l,
      16, 0, 0);
}

// =====================================================================
// BK=64 bf16 NT GEMM template: C[M,N] = A[M,K]*B[N,K]^T (+bias).
// Rationale (R2-R9 ledger): wall ~= rounds x slices x (sync_floor ~2000cyc
// + pipe work); sync floor is per-slice and schedule-invariant (6 failed
// structures). BK=64 HALVES slice count (12 vs 24) with the same dead-
// simple 1-barrier/slice loop. Ring-2 double buffer; per-slice vmcnt(0)
// is cheap because the batch had a full slice (~2000-4000cyc >> 900cyc
// HBM) to land.
//   G1: BM=BN=256, 8 waves (2x4), wave 128x64, LDS 128KB, 1 blk/CU.
//   G2: BM=BN=128, 4 waves (2x2), wave  64x64, LDS  64KB, 2 blk/CU.
// Layout: slot rows of 128B (64 bf16); LDS(r, slot8 s) = global(r,
// s^(r&7)) via pre-swizzled source + swizzled ds_read (involution class
// verified R3/R6: conflicts=0; 16-lane beat = 8 slots x 2 lanes = free).
// Operand-swapped MFMA: lane's 4 acc regs = 4 consecutive out cols ->
// vector stores (verified R6). Frag reads split per K-half to cap VGPR.
// =====================================================================
template <int BM, int BN, int WM, int WN, bool OUT_F32>
__global__ __launch_bounds__(WM * WN * 64, 2)
void gemm_bk64(const u16* __restrict__ A, const u16* __restrict__ Bw,
               void* __restrict__ Cout, const float* __restrict__ bias,
               int Ndim, int K) {
  constexpr int NT = WM * WN * 64;          // threads
  constexpr int MF = BM / WM / 16;          // A frags per wave
  constexpr int NF = BN / WN / 16;          // B frags per wave
  constexpr int SLOT = (BM + BN) * 128;     // bytes per K-slice
  static_assert(4 * (NT / 8) == BM && BM == BN, "staging geometry");
  __shared__ char lds[2 * SLOT];

  const int nTn = Ndim / BN;
  const int nwg = gridDim.x;
  const int bid = blockIdx.x;
  const int wgid = (bid & 7) * (nwg >> 3) + (bid >> 3);   // XCD swizzle (nwg%8==0)
  const int tm = wgid / nTn, tn = wgid % nTn;

  const int t = threadIdx.x;
  const int l = t & 63;
  const int w = t >> 6;
  const int wr = w / WN;
  const int wc = w % WN;

  const int NSL = K >> 6;                   // 64-wide K slices (12)

  // staging: thread t stages 8 chunks (4 A + 4 B), chunk k at LDS byte
  // (k*NT+t)*16; row = k*(NT/8) + (t>>3); source slot pre-swizzled.
  const int srA = t >> 3;
  const int sw8 = ((t & 7) ^ ((t >> 3) & 7)) * 8;   // elem offset in 64-elem row
  const u16* baseA = A  + (size_t)(tm * BM) * K + sw8;
  const u16* baseB = Bw + (size_t)(tn * BN) * K + sw8;

  // swizzled ds_read lane terms (row&7 == l&7 since all row bases are mult 8)
  const int lt0 = (l & 15) * 128 + (((l >> 4)    ) ^ (l & 7)) * 16;  // K-half 0
  const int lt1 = (l & 15) * 128 + (((l >> 4) + 4) ^ (l & 7)) * 16;  // K-half 1

  f32x4 acc[MF][NF];
  #pragma unroll
  for (int m = 0; m < MF; ++m)
    #pragma unroll
    for (int n = 0; n < NF; ++n)
      acc[m][n] = f32x4{0.f, 0.f, 0.f, 0.f};

#define STAGE(SL, P)                                                          \
  do {                                                                        \
    char* d = lds + (SL) * SLOT + t * 16;                                     \
    const size_t ko = (size_t)(P) * 64;                                       \
    _Pragma("unroll")                                                         \
    for (int k = 0; k < 4; ++k)                                               \
      gload_lds16(baseA + (size_t)(k * (NT / 8) + srA) * K + ko,              \
                  d + k * NT * 16);                                           \
    _Pragma("unroll")                                                         \
    for (int k = 0; k < 4; ++k)                                               \
      gload_lds16(baseB + (size_t)(k * (NT / 8) + srA) * K + ko,              \
                  d + (k + 4) * NT * 16);                                     \
  } while (0)

  STAGE(0, 0);   // prologue

  for (int p = 0; p < NSL; ++p) {
    asm volatile("s_waitcnt vmcnt(0)" ::: "memory");   // batch(p) landed (all waves)
    __builtin_amdgcn_s_barrier();                      // -> slot p&1 visible

    const char* ab = lds + (p & 1) * SLOT + wr * (BM / WM) * 128;
    const char* bb = lds + (p & 1) * SLOT + BM * 128 + wc * (BN / WN) * 128;

    bf16x8 af[MF], bf[NF];
    // ---- K-half 0 ----
    #pragma unroll
    for (int m = 0; m < MF; ++m)
      af[m] = *reinterpret_cast<const bf16x8*>(ab + m * 2048 + lt0);
    #pragma unroll
    for (int n = 0; n < NF; ++n)
      bf[n] = *reinterpret_cast<const bf16x8*>(bb + n * 2048 + lt0);

    if (p + 1 < NSL) STAGE((p + 1) & 1, p + 1);        // fly during both MFMA groups

    __builtin_amdgcn_s_setprio(1);
    #pragma unroll
    for (int m = 0; m < MF; ++m)
      #pragma unroll
      for (int n = 0; n < NF; ++n)
        acc[m][n] = __builtin_amdgcn_mfma_f32_16x16x32_bf16(bf[n], af[m],
                                                            acc[m][n], 0, 0, 0);
    __builtin_amdgcn_s_setprio(0);

    // ---- K-half 1 ----
    #pragma unroll
    for (int m = 0; m < MF; ++m)
      af[m] = *reinterpret_cast<const bf16x8*>(ab + m * 2048 + lt1);
    #pragma unroll
    for (int n = 0; n < NF; ++n)
      bf[n] = *reinterpret_cast<const bf16x8*>(bb + n * 2048 + lt1);

    __builtin_amdgcn_s_setprio(1);
    #pragma unroll
    for (int m = 0; m < MF; ++m)
      #pragma unroll
      for (int n = 0; n < NF; ++n)
        acc[m][n] = __builtin_amdgcn_mfma_f32_16x16x32_bf16(bf[n], af[m],
                                                            acc[m][n], 0, 0, 0);
    __builtin_amdgcn_s_setprio(0);
    // no trailing barrier: batch(p+1) targets the OTHER slot; its old
    // readers (slice p-1) retired before barrier(p), and the issue is
    // after barrier(p). Next slice's vmcnt(0)+barrier completes the ring.
  }
#undef STAGE

  // epilogue (operand-swapped layout, verified R6): lane l, frag (m,n),
  // reg j -> C[m*16 + (l&15)][n*16 + (l>>4)*4 + j]; 4 consecutive cols.
  const int grow0 = tm * BM + wr * (BM / WM) + (l & 15);
  const int gcol0 = tn * BN + wc * (BN / WN) + (l >> 4) * 4;
  #pragma unroll
  for (int m = 0; m < MF; ++m) {
    const int row = grow0 + m * 16;
    #pragma unroll
    for (int n = 0; n < NF; ++n) {
      const int col = gcol0 + n * 16;
      if constexpr (OUT_F32) {
        float* O = (float*)Cout;
        const float4 bv = *reinterpret_cast<const float4*>(&bias[col]);
        float4 o;
        o.x = acc[m][n][0] + bv.x;
        o.y = acc[m][n][1] + bv.y;
        o.z = acc[m][n][2] + bv.z;
        o.w = acc[m][n][3] + bv.w;
        *reinterpret_cast<float4*>(&O[(size_t)row * Ndim + col]) = o;
      } else {
        u16* O = (u16*)Cout;
        ushort4 o;
        o.x = f2bf_rne(acc[m][n][0]);
        o.y = f2bf_rne(acc[m][n][1]);
        o.z = f2bf_rne(acc[m][n][2]);
        o.w = f2bf_rne(acc[m][n][3]);
        *reinterpret_cast<ushort4*>(&O[(size_t)row * Ndim + col]) = o;
      }
    }
  }
}

// =====================================================================
// local 3x3 dilated attention, 4x-vectorized (R9, verified): one wave
// per (dil,b,w) handles all 4 heads; ushort4 loads/stores; 16-lane
// shfl_xor dot reduce.
// =====================================================================
__global__ __launch_bounds__(256)
void attn_local4(const u16* __restrict__ qkv, u16* __restrict__ y) {
  const int t = threadIdx.x;
  const int l = t & 63;
  int wid = blockIdx.x * 4 + (t >> 6);      // [0, 3*8*1024)
  const int w = wid & (NB - 1); wid >>= 10;
  const int b = wid & 7; wid >>= 3;
  const int dil = wid;                      // 0..2

  const int colq = dil * 256 + l * 4;       // 4 consecutive dims, head l>>4
  float q[3][4], k[3][4], v[3][4];
  #pragma unroll
  for (int i = 0; i < 3; ++i) {
    const size_t row = (size_t)(b * Nn + i * NB + w) * C3;
    const ushort4 q4 = *reinterpret_cast<const ushort4*>(&qkv[row + colq]);
    const ushort4 k4 = *reinterpret_cast<const ushort4*>(&qkv[row + 768 + colq]);
    const ushort4 v4 = *reinterpret_cast<const ushort4*>(&qkv[row + 1536 + colq]);
    q[i][0] = bf2f(q4.x); q[i][1] = bf2f(q4.y); q[i][2] = bf2f(q4.z); q[i][3] = bf2f(q4.w);
    k[i][0] = bf2f(k4.x); k[i][1] = bf2f(k4.y); k[i][2] = bf2f(k4.z); k[i][3] = bf2f(k4.w);
    v[i][0] = bf2f(v4.x); v[i][1] = bf2f(v4.y); v[i][2] = bf2f(v4.z); v[i][3] = bf2f(v4.w);
  }

  float s[3][3];
  #pragma unroll
  for (int i = 0; i < 3; ++i)
    #pragma unroll
    for (int j = 0; j < 3; ++j) {
      float p = q[i][0] * k[j][0] + q[i][1] * k[j][1]
              + q[i][2] * k[j][2] + q[i][3] * k[j][3];
      p += __shfl_xor(p, 1, 64);
      p += __shfl_xor(p, 2, 64);
      p += __shfl_xor(p, 4, 64);
      p += __shfl_xor(p, 8, 64);
      s[i][j] = p * 0.125f;   // hd=64 -> scale 1/8
    }

  #pragma unroll
  for (int i = 0; i < 3; ++i) {
    const float mx = fmaxf(fmaxf(s[i][0], s[i][1]), s[i][2]);
    const float e0 = __expf(s[i][0] - mx);
    const float e1 = __expf(s[i][1] - mx);
    const float e2 = __expf(s[i][2] - mx);
    const float inv = 1.0f / (e0 + e1 + e2);
    ushort4 o4;
    u16* po = &o4.x;
    #pragma unroll
    for (int e = 0; e < 4; ++e)
      po[e] = f2bf_rne((e0 * v[0][e] + e1 * v[1][e] + e2 * v[2][e]) * inv);
    const int linear = (l >> 4) * 192 + i * 64 + (l & 15) * 4;
    const int nout = w * 3 + (linear >> 8);
    const int dd = linear & 255;
    *reinterpret_cast<ushort4*>(
        &y[(size_t)(b * Nn + nout) * Cc + dil * 256 + dd]) = o4;
  }
}

extern "C" void kernel_launch(void* const* d_in, const int* in_sizes, int n_in,
                              void* d_out, int out_size, void* d_ws, size_t ws_size,
                              hipStream_t stream) {
  const float* x      = (const float*)d_in[0];
  const float* qkv_w  = (const float*)d_in[1];
  const float* proj_w = (const float*)d_in[2];
  const float* proj_b = (const float*)d_in[3];

  char* ws = (char*)d_ws;
  u16* wq_b = (u16*)(ws);                      //  2304*768 bf16
  u16* wp_b = (u16*)(ws + 3538944);            //   768*768 bf16
  u16* xb   = (u16*)(ws + 4718592);            // 24576*768 bf16 (reused as yb)
  u16* qkvb = (u16*)(ws + 42467328);           // 24576*2304 bf16
  u16* yb   = xb;

  cvt_all<<<2048, 256, 0, stream>>>((const float4*)x, (const float4*)qkv_w,
                                    (const float4*)proj_w, (ushort4*)xb,
                                    (ushort4*)wq_b, (ushort4*)wp_b);

  // GEMM1: qkvb[M,2304] = xb[M,768] @ wq_b[2304,768]^T
  // 256^2 tile, BK=64, 864 blocks, 8 waves, 1 blk/CU
  gemm_bk64<256, 256, 2, 4, false>
      <<<(Mr / 256) * (C3 / 256), 512, 0, stream>>>(xb, wq_b, qkvb, nullptr, C3, Cc);

  // attention: 24576 wave-groups (4 heads each), 4 per block
  attn_local4<<<(3 * 8 * 1024) / 4, 256, 0, stream>>>(qkvb, yb);

  // GEMM2: out[M,768] = yb[M,768] @ wp_b[768,768]^T + proj_b
  // 128^2 tile, BK=64, 1152 blocks, 4 waves, 2 blk/CU
  gemm_bk64<128, 128, 2, 2, true>
      <<<(Mr / 128) * (Cc / 128), 256, 0, stream>>>(yb, wp_b, d_out, proj_b, Cc, Cc);
}

// Round 11
// 196.450 us; speedup vs baseline: 1.3791x; 1.0344x over previous
//
#include <hip/hip_runtime.h>
#include <stdint.h>

#define DEVFN __device__ __forceinline__

typedef unsigned short u16;
typedef __bf16 bf16_t;
typedef bf16_t bf16x8 __attribute__((ext_vector_type(8)));
typedef float  f32x4  __attribute__((ext_vector_type(4)));

static constexpr int Bb = 8, Nn = 3072, Cc = 768;
static constexpr int Mr = Bb * Nn;      // 24576 rows
static constexpr int C3 = 3 * Cc;       // 2304
static constexpr int NB = 1024;         // dilation stride

DEVFN u16 f2bf_rne(float f) {
  uint32_t u = __builtin_bit_cast(uint32_t, f);
  u += 0x7FFFu + ((u >> 16) & 1u);
  return (u16)(u >> 16);
}
DEVFN float bf2f(u16 v) {
  uint32_t u = ((uint32_t)v) << 16;
  return __builtin_bit_cast(float, u);
}

// ---------------- fused f32 -> bf16 converts ----------------
__global__ void cvt_all(const float4* __restrict__ x, const float4* __restrict__ wq,
                        const float4* __restrict__ wp, ushort4* __restrict__ xb,
                        ushort4* __restrict__ wqb, ushort4* __restrict__ wpb) {
  const int NX = Mr * Cc / 4, NQ = C3 * Cc / 4, NP = Cc * Cc / 4;
  int i = blockIdx.x * blockDim.x + threadIdx.x;
  const int stride = gridDim.x * blockDim.x;
  for (; i < NX + NQ + NP; i += stride) {
    const float4* src; ushort4* dst; int j;
    if (i < NX)           { src = x;  dst = xb;  j = i; }
    else if (i < NX + NQ) { src = wq; dst = wqb; j = i - NX; }
    else                  { src = wp; dst = wpb; j = i - NX - NQ; }
    float4 v = src[j];
    ushort4 o;
    o.x = f2bf_rne(v.x); o.y = f2bf_rne(v.y);
    o.z = f2bf_rne(v.z); o.w = f2bf_rne(v.w);
    dst[j] = o;
  }
}

// ---------------- async global->LDS, 16B per lane ----------------
DEVFN void gload_lds16(const void* g, void* l) {
  __builtin_amdgcn_global_load_lds(
      (const __attribute__((address_space(1))) uint32_t*)g,
      (__attribute__((address_space(3))) uint32_t*)l,
      16, 0, 0);
}

// =====================================================================
// 256x256 bf16 NT GEMM — R2 VERBATIM. Empirical best for GEMM1: 108.6 us,
// reproduced three times (R2/R9/R9-groups). Ledger: 7 alternative
// structures (swizzle-fix, operand-swap, sub-phases, 128-tile 3blk/CU,
// 16-wave, BK=64 8-phase, BK=64 dbuf) ALL regressed to 115-141 us.
// 8 waves, 4-slot K=32-slice ring, counted vmcnt(8) (~2 slices of
// latency tolerance), 1 barrier/slice. DO NOT TOUCH.
// =====================================================================
template <bool OUT_F32>
__global__ __launch_bounds__(512, 2)
void gemm256(const u16* __restrict__ A, const u16* __restrict__ Bw,
             void* __restrict__ Cout, const float* __restrict__ bias,
             int Ndim, int K) {
  constexpr int SLOT = 32768;
  __shared__ char lds[4 * SLOT];   // 128 KiB

  const int nTn = Ndim >> 8;
  const int nwg = gridDim.x;
  const int bid = blockIdx.x;
  const int wgid = (bid & 7) * (nwg >> 3) + (bid >> 3);   // XCD swizzle (nwg%8==0)
  const int tm = wgid / nTn, tn = wgid % nTn;

  const int t = threadIdx.x;
  const int l = t & 63;
  const int w = t >> 6;
  const int wr = w >> 2;         // M half of tile
  const int wcq = w & 3;         // N quarter of tile
  const int lr = l & 15;

  const int NPH = K >> 5;

  const int srow = l >> 2;
  const int scol = 8 * ((l & 3) ^ (srow & 3));
  const u16* pA0 = A  + (size_t)(tm * 256 +       w * 16 + srow) * K + scol;
  const u16* pA1 = A  + (size_t)(tm * 256 + 128 + w * 16 + srow) * K + scol;
  const u16* pB0 = Bw + (size_t)(tn * 256 +       w * 16 + srow) * K + scol;
  const u16* pB1 = Bw + (size_t)(tn * 256 + 128 + w * 16 + srow) * K + scol;

  const int lane_off = lr * 64 + (((l >> 4) * 16) ^ ((lr & 3) << 4));

  f32x4 acc[8][4];
  #pragma unroll
  for (int m = 0; m < 8; ++m)
    #pragma unroll
    for (int n = 0; n < 4; ++n)
      acc[m][n] = f32x4{0.f, 0.f, 0.f, 0.f};

  #pragma unroll
  for (int q = 0; q < 3; ++q) {
    char* dA = &lds[q * SLOT + w * 1024];
    char* dB = &lds[q * SLOT + 16384 + w * 1024];
    const size_t ko = (size_t)q * 32;
    gload_lds16(pA0 + ko, dA);
    gload_lds16(pA1 + ko, dA + 8192);
    gload_lds16(pB0 + ko, dB);
    gload_lds16(pB1 + ko, dB + 8192);
  }

#define GPHASE(VMSTR, PF_COND)                                                \
  do {                                                                        \
    asm volatile(VMSTR ::: "memory");                                         \
    __builtin_amdgcn_s_barrier();                                             \
    asm volatile("" ::: "memory");                                            \
    const char* ab = &lds[(p & 3) * SLOT] + wr * 8192 + lane_off;             \
    const char* bb = &lds[(p & 3) * SLOT + 16384] + wcq * 4096 + lane_off;    \
    bf16x8 af[8], bf[4];                                                      \
    _Pragma("unroll")                                                         \
    for (int m = 0; m < 8; ++m)                                               \
      af[m] = *reinterpret_cast<const bf16x8*>(ab + m * 1024);                \
    _Pragma("unroll")                                                         \
    for (int n = 0; n < 4; ++n)                                               \
      bf[n] = *reinterpret_cast<const bf16x8*>(bb + n * 1024);                \
    if (PF_COND) {                                                            \
      const int ps = (p + 3) & 3;                                             \
      char* dA = &lds[ps * SLOT + w * 1024];                                  \
      char* dB = &lds[ps * SLOT + 16384 + w * 1024];                          \
      const size_t ko = (size_t)(p + 3) * 32;                                 \
      gload_lds16(pA0 + ko, dA);                                              \
      gload_lds16(pA1 + ko, dA + 8192);                                       \
      gload_lds16(pB0 + ko, dB);                                              \
      gload_lds16(pB1 + ko, dB + 8192);                                       \
    }                                                                         \
    __builtin_amdgcn_s_setprio(1);                                            \
    _Pragma("unroll")                                                         \
    for (int m = 0; m < 8; ++m)                                               \
      _Pragma("unroll")                                                       \
      for (int n = 0; n < 4; ++n)                                             \
        acc[m][n] = __builtin_amdgcn_mfma_f32_16x16x32_bf16(af[m], bf[n],     \
                                                            acc[m][n], 0,0,0);\
    __builtin_amdgcn_s_setprio(0);                                            \
    asm volatile("" ::: "memory");                                            \
  } while (0)

  int p = 0;
  for (; p < NPH - 2; ++p) GPHASE("s_waitcnt vmcnt(8)", (p + 3 < NPH));
  GPHASE("s_waitcnt vmcnt(4)", false); ++p;
  GPHASE("s_waitcnt vmcnt(0)", false); ++p;
#undef GPHASE

  // epilogue: C/D layout col=lane&15, row=(lane>>4)*4+j
  const int rbase = tm * 256 + wr * 128 + (l >> 4) * 4;
  #pragma unroll
  for (int m = 0; m < 8; ++m) {
    #pragma unroll
    for (int n = 0; n < 4; ++n) {
      const int col = tn * 256 + wcq * 64 + n * 16 + lr;
      const int row0 = rbase + m * 16;
      if constexpr (OUT_F32) {
        float* O = (float*)Cout;
        const float bv = bias[col];
        #pragma unroll
        for (int j = 0; j < 4; ++j)
          O[(size_t)(row0 + j) * Ndim + col] = acc[m][n][j] + bv;
      } else {
        u16* O = (u16*)Cout;
        #pragma unroll
        for (int j = 0; j < 4; ++j)
          O[(size_t)(row0 + j) * Ndim + col] = f2bf_rne(acc[m][n][j]);
      }
    }
  }
}

// =====================================================================
// 128x128 bf16 NT GEMM, BK=64, 4 waves, 2-slot dbuf, 2 blocks/CU
// (R10, verified: improved GEMM2 by ~8 us vs R6 gemm128).
// =====================================================================
template <int BM, int BN, int WM, int WN, bool OUT_F32>
__global__ __launch_bounds__(WM * WN * 64, 2)
void gemm_bk64(const u16* __restrict__ A, const u16* __restrict__ Bw,
               void* __restrict__ Cout, const float* __restrict__ bias,
               int Ndim, int K) {
  constexpr int NT = WM * WN * 64;
  constexpr int MF = BM / WM / 16;
  constexpr int NF = BN / WN / 16;
  constexpr int SLOT = (BM + BN) * 128;
  static_assert(4 * (NT / 8) == BM && BM == BN, "staging geometry");
  __shared__ char lds[2 * SLOT];

  const int nTn = Ndim / BN;
  const int nwg = gridDim.x;
  const int bid = blockIdx.x;
  const int wgid = (bid & 7) * (nwg >> 3) + (bid >> 3);
  const int tm = wgid / nTn, tn = wgid % nTn;

  const int t = threadIdx.x;
  const int l = t & 63;
  const int w = t >> 6;
  const int wr = w / WN;
  const int wc = w % WN;

  const int NSL = K >> 6;

  const int srA = t >> 3;
  const int sw8 = ((t & 7) ^ ((t >> 3) & 7)) * 8;
  const u16* baseA = A  + (size_t)(tm * BM) * K + sw8;
  const u16* baseB = Bw + (size_t)(tn * BN) * K + sw8;

  const int lt0 = (l & 15) * 128 + (((l >> 4)    ) ^ (l & 7)) * 16;
  const int lt1 = (l & 15) * 128 + (((l >> 4) + 4) ^ (l & 7)) * 16;

  f32x4 acc[MF][NF];
  #pragma unroll
  for (int m = 0; m < MF; ++m)
    #pragma unroll
    for (int n = 0; n < NF; ++n)
      acc[m][n] = f32x4{0.f, 0.f, 0.f, 0.f};

#define STAGE(SL, P)                                                          \
  do {                                                                        \
    char* d = lds + (SL) * SLOT + t * 16;                                     \
    const size_t ko = (size_t)(P) * 64;                                       \
    _Pragma("unroll")                                                         \
    for (int k = 0; k < 4; ++k)                                               \
      gload_lds16(baseA + (size_t)(k * (NT / 8) + srA) * K + ko,              \
                  d + k * NT * 16);                                           \
    _Pragma("unroll")                                                         \
    for (int k = 0; k < 4; ++k)                                               \
      gload_lds16(baseB + (size_t)(k * (NT / 8) + srA) * K + ko,              \
                  d + (k + 4) * NT * 16);                                     \
  } while (0)

  STAGE(0, 0);

  for (int p = 0; p < NSL; ++p) {
    asm volatile("s_waitcnt vmcnt(0)" ::: "memory");
    __builtin_amdgcn_s_barrier();

    const char* ab = lds + (p & 1) * SLOT + wr * (BM / WM) * 128;
    const char* bb = lds + (p & 1) * SLOT + BM * 128 + wc * (BN / WN) * 128;

    bf16x8 af[MF], bf[NF];
    #pragma unroll
    for (int m = 0; m < MF; ++m)
      af[m] = *reinterpret_cast<const bf16x8*>(ab + m * 2048 + lt0);
    #pragma unroll
    for (int n = 0; n < NF; ++n)
      bf[n] = *reinterpret_cast<const bf16x8*>(bb + n * 2048 + lt0);

    if (p + 1 < NSL) STAGE((p + 1) & 1, p + 1);

    __builtin_amdgcn_s_setprio(1);
    #pragma unroll
    for (int m = 0; m < MF; ++m)
      #pragma unroll
      for (int n = 0; n < NF; ++n)
        acc[m][n] = __builtin_amdgcn_mfma_f32_16x16x32_bf16(bf[n], af[m],
                                                            acc[m][n], 0, 0, 0);
    __builtin_amdgcn_s_setprio(0);

    #pragma unroll
    for (int m = 0; m < MF; ++m)
      af[m] = *reinterpret_cast<const bf16x8*>(ab + m * 2048 + lt1);
    #pragma unroll
    for (int n = 0; n < NF; ++n)
      bf[n] = *reinterpret_cast<const bf16x8*>(bb + n * 2048 + lt1);

    __builtin_amdgcn_s_setprio(1);
    #pragma unroll
    for (int m = 0; m < MF; ++m)
      #pragma unroll
      for (int n = 0; n < NF; ++n)
        acc[m][n] = __builtin_amdgcn_mfma_f32_16x16x32_bf16(bf[n], af[m],
                                                            acc[m][n], 0, 0, 0);
    __builtin_amdgcn_s_setprio(0);
  }
#undef STAGE

  const int grow0 = tm * BM + wr * (BM / WM) + (l & 15);
  const int gcol0 = tn * BN + wc * (BN / WN) + (l >> 4) * 4;
  #pragma unroll
  for (int m = 0; m < MF; ++m) {
    const int row = grow0 + m * 16;
    #pragma unroll
    for (int n = 0; n < NF; ++n) {
      const int col = gcol0 + n * 16;
      if constexpr (OUT_F32) {
        float* O = (float*)Cout;
        const float4 bv = *reinterpret_cast<const float4*>(&bias[col]);
        float4 o;
        o.x = acc[m][n][0] + bv.x;
        o.y = acc[m][n][1] + bv.y;
        o.z = acc[m][n][2] + bv.z;
        o.w = acc[m][n][3] + bv.w;
        *reinterpret_cast<float4*>(&O[(size_t)row * Ndim + col]) = o;
      } else {
        u16* O = (u16*)Cout;
        ushort4 o;
        o.x = f2bf_rne(acc[m][n][0]);
        o.y = f2bf_rne(acc[m][n][1]);
        o.z = f2bf_rne(acc[m][n][2]);
        o.w = f2bf_rne(acc[m][n][3]);
        *reinterpret_cast<ushort4*>(&O[(size_t)row * Ndim + col]) = o;
      }
    }
  }
}

// =====================================================================
// local 3x3 dilated attention, 4x-vectorized (R9, verified).
// =====================================================================
__global__ __launch_bounds__(256)
void attn_local4(const u16* __restrict__ qkv, u16* __restrict__ y) {
  const int t = threadIdx.x;
  const int l = t & 63;
  int wid = blockIdx.x * 4 + (t >> 6);      // [0, 3*8*1024)
  const int w = wid & (NB - 1); wid >>= 10;
  const int b = wid & 7; wid >>= 3;
  const int dil = wid;                      // 0..2

  const int colq = dil * 256 + l * 4;       // 4 consecutive dims, head l>>4
  float q[3][4], k[3][4], v[3][4];
  #pragma unroll
  for (int i = 0; i < 3; ++i) {
    const size_t row = (size_t)(b * Nn + i * NB + w) * C3;
    const ushort4 q4 = *reinterpret_cast<const ushort4*>(&qkv[row + colq]);
    const ushort4 k4 = *reinterpret_cast<const ushort4*>(&qkv[row + 768 + colq]);
    const ushort4 v4 = *reinterpret_cast<const ushort4*>(&qkv[row + 1536 + colq]);
    q[i][0] = bf2f(q4.x); q[i][1] = bf2f(q4.y); q[i][2] = bf2f(q4.z); q[i][3] = bf2f(q4.w);
    k[i][0] = bf2f(k4.x); k[i][1] = bf2f(k4.y); k[i][2] = bf2f(k4.z); k[i][3] = bf2f(k4.w);
    v[i][0] = bf2f(v4.x); v[i][1] = bf2f(v4.y); v[i][2] = bf2f(v4.z); v[i][3] = bf2f(v4.w);
  }

  float s[3][3];
  #pragma unroll
  for (int i = 0; i < 3; ++i)
    #pragma unroll
    for (int j = 0; j < 3; ++j) {
      float p = q[i][0] * k[j][0] + q[i][1] * k[j][1]
              + q[i][2] * k[j][2] + q[i][3] * k[j][3];
      p += __shfl_xor(p, 1, 64);
      p += __shfl_xor(p, 2, 64);
      p += __shfl_xor(p, 4, 64);
      p += __shfl_xor(p, 8, 64);
      s[i][j] = p * 0.125f;   // hd=64 -> scale 1/8
    }

  #pragma unroll
  for (int i = 0; i < 3; ++i) {
    const float mx = fmaxf(fmaxf(s[i][0], s[i][1]), s[i][2]);
    const float e0 = __expf(s[i][0] - mx);
    const float e1 = __expf(s[i][1] - mx);
    const float e2 = __expf(s[i][2] - mx);
    const float inv = 1.0f / (e0 + e1 + e2);
    ushort4 o4;
    u16* po = &o4.x;
    #pragma unroll
    for (int e = 0; e < 4; ++e)
      po[e] = f2bf_rne((e0 * v[0][e] + e1 * v[1][e] + e2 * v[2][e]) * inv);
    const int linear = (l >> 4) * 192 + i * 64 + (l & 15) * 4;
    const int nout = w * 3 + (linear >> 8);
    const int dd = linear & 255;
    *reinterpret_cast<ushort4*>(
        &y[(size_t)(b * Nn + nout) * Cc + dil * 256 + dd]) = o4;
  }
}

extern "C" void kernel_launch(void* const* d_in, const int* in_sizes, int n_in,
                              void* d_out, int out_size, void* d_ws, size_t ws_size,
                              hipStream_t stream) {
  const float* x      = (const float*)d_in[0];
  const float* qkv_w  = (const float*)d_in[1];
  const float* proj_w = (const float*)d_in[2];
  const float* proj_b = (const float*)d_in[3];

  char* ws = (char*)d_ws;
  u16* wq_b = (u16*)(ws);                      //  2304*768 bf16
  u16* wp_b = (u16*)(ws + 3538944);            //   768*768 bf16
  u16* xb   = (u16*)(ws + 4718592);            // 24576*768 bf16 (reused as yb)
  u16* qkvb = (u16*)(ws + 42467328);           // 24576*2304 bf16
  u16* yb   = xb;

  cvt_all<<<2048, 256, 0, stream>>>((const float4*)x, (const float4*)qkv_w,
                                    (const float4*)proj_w, (ushort4*)xb,
                                    (ushort4*)wq_b, (ushort4*)wp_b);

  // GEMM1: qkvb[M,2304] = xb[M,768] @ wq_b[2304,768]^T   (R2 verbatim, 864 blocks)
  gemm256<false><<<(Mr / 256) * (C3 / 256), 512, 0, stream>>>(xb, wq_b, qkvb, nullptr, C3, Cc);

  // attention: 24576 wave-groups (4 heads each), 4 per block
  attn_local4<<<(3 * 8 * 1024) / 4, 256, 0, stream>>>(qkvb, yb);

  // GEMM2: out[M,768] = yb[M,768] @ wp_b[768,768]^T + proj_b
  // 128^2 tile, BK=64, 1152 blocks, 4 waves, 2 blk/CU (R10, verified)
  gemm_bk64<128, 128, 2, 2, true>
      <<<(Mr / 128) * (Cc / 128), 256, 0, stream>>>(yb, wp_b, d_out, proj_b, Cc, Cc);
}